// Round 16
// baseline (364.524 us; speedup 1.0000x reference)
//
#include <hip/hip_runtime.h>
#include <math.h>

// ---------------------------------------------------------------------------
// HyperbolicGraphConvolution (HGCN HypLinear + NodeSelect + HypAct), c=1.
// Round 16: gemmprep occupancy fix. R15 landed at 51% occ (24KB LDS -> 6
// blk/CU) and missed its prediction. Now 512-thread blocks, NPB=64 (same 8
// nodes/wave, identical per-wave FMA order -> mx/keys bit-identical): 32KB
// LDS/block -> 4 blk/CU x 8 waves = 32 waves/CU (100%), W-staging amortized
// over 8 waves. Everything else identical to R15.
// ---------------------------------------------------------------------------

#define MAXN_D 0.996      // (1 - 4e-3)/sqrt(c), c=1
#define MAXN_F 0.996f
#define NPB 64            // nodes per block in k_gemmprep (8 per wave, 8 waves)
#define GPT 512           // gemmprep threads per block
#define NBMAX 512         // max buckets (N <= 131072)
#define BCAP 6144         // static bucket capacity (mean 3072, sigma 55)
#define BINBLK 256        // blocks in bin kernels
#define SELB 128          // blocks per select level
#define SBIN 8192         // 13-bit radix bins
#define CAND_CAP 16384    // finish-stage candidate cap (expect ~12)

typedef unsigned long long ull;

__device__ __forceinline__ double wsumd(double v){
#pragma unroll
  for(int o=32;o;o>>=1) v += __shfl_xor(v,o,64);
  return v;
}
__device__ __forceinline__ float wsumf(float v){
#pragma unroll
  for(int o=32;o;o>>=1) v += __shfl_xor(v,o,64);
  return v;
}
__device__ __forceinline__ double qsumd(double v){
#pragma unroll
  for(int o=1;o<16;o<<=1) v += __shfl_xor(v,o,64);
  return v;
}
__device__ __forceinline__ float qsumf(float v){
#pragma unroll
  for(int o=1;o<16;o<<=1) v += __shfl_xor(v,o,64);
  return v;
}
__device__ __forceinline__ double gsumd(double v){
  v += __shfl_xor(v,16,64); v += __shfl_xor(v,32,64); return v;
}
__device__ __forceinline__ float gsumf(float v){
  v += __shfl_xor(v,16,64); v += __shfl_xor(v,32,64); return v;
}

// ---- K0: hyp_bias (double) + |hb|^2 + rem + static bucket cursors ----------
__global__ __launch_bounds__(256) void k_init(
    const float* __restrict__ bias, double* __restrict__ hb,
    double* __restrict__ hb2, int* __restrict__ rem, int kth,
    int* __restrict__ dstCur, int* __restrict__ srcCur, int NB){
  if(threadIdx.x < 64){
    int lane = threadIdx.x;
    double b = (double)bias[lane];
    double n = fmax(sqrt(wsumd(b*b)), 1e-15);
    double e = tanh(n)*b/n;                       // expmap0, sc=1
    double en = fmax(sqrt(wsumd(e*e)), 1e-15);
    if(en > MAXN_D) e *= MAXN_D/en;               // proj
    hb[lane] = e;
    double s2 = wsumd(e*e);
    if(lane==0) *hb2 = s2;
  }
  if(threadIdx.x == 0) *rem = kth;
  for(int b=threadIdx.x; b<NB; b+=256){
    dstCur[b] = b*BCAP;
    srcCur[b] = b*BCAP;
  }
}

// ---- K1: bin place into static-cap regions (line-dense binned writes) ------
__global__ __launch_bounds__(256) void k_binPlace(const int* __restrict__ ei, int E,
    int NB, int chunk, int* __restrict__ dstCur, int* __restrict__ srcCur,
    ull* __restrict__ dstbin, int* __restrict__ srcbin){
  __shared__ int dh[NBMAX], sh_[NBMAX];
  __shared__ int db[NBMAX], sb[NBMAX];
  for(int t=threadIdx.x; t<NB; t+=256){ dh[t]=0; sh_[t]=0; }
  __syncthreads();
  int start = blockIdx.x*chunk, end = min(E, start+chunk);
  for(int e=start+(int)threadIdx.x; e<end; e+=256){
    int s = ei[e], d = ei[(size_t)E+e];
    atomicAdd(&dh[d>>8],1);
    if(s!=d) atomicAdd(&sh_[s>>8],1);
  }
  __syncthreads();
  for(int t=threadIdx.x; t<NB; t+=256){
    db[t] = dh[t]  ? atomicAdd(&dstCur[t], dh[t])  : 0;
    sb[t] = sh_[t] ? atomicAdd(&srcCur[t], sh_[t]) : 0;
  }
  __syncthreads();
  for(int t=threadIdx.x; t<NB; t+=256){ dh[t]=db[t]; sh_[t]=sb[t]; }
  __syncthreads();
  for(int e=start+(int)threadIdx.x; e<end; e+=256){
    int s = ei[e], d = ei[(size_t)E+e];
    int p = atomicAdd(&dh[d>>8],1);
    dstbin[p] = ((ull)(unsigned)d<<32) | (unsigned)s;
    if(s!=d){ int p2 = atomicAdd(&sh_[s>>8],1); srcbin[p2] = s; }
  }
}

// ---- K2: per bucket: dst->rowbeg/rowcnt/csr, then src->dinv ----------------
__global__ __launch_bounds__(256) void k_bucketAB(
    const ull* __restrict__ dstbin, const int* __restrict__ dstCur,
    int* __restrict__ rowbeg, int* __restrict__ rowcnt, int* __restrict__ csr,
    const int* __restrict__ srcbin, const int* __restrict__ srcCur,
    double* __restrict__ dinv, int N){
  int b = blockIdx.x;
  int node0 = b<<8;
  int nodes = min(256, N-node0);
  __shared__ int c[256], ex[256];
  int t = threadIdx.x;
  {
    int base = b*BCAP, cnt = dstCur[b]-base;
    c[t]=0; __syncthreads();
    for(int e=base+t; e<base+cnt; e+=256){
      int d = (int)(dstbin[e]>>32);
      atomicAdd(&c[d-node0],1);
    }
    __syncthreads();
    int v = c[t]; ex[t]=v; __syncthreads();
    for(int off=1; off<256; off<<=1){
      int a = (t>=off) ? ex[t-off] : 0; __syncthreads();
      ex[t] += a; __syncthreads();
    }
    int mybase = base + ex[t] - v;
    if(t<nodes){ rowbeg[node0+t] = mybase; rowcnt[node0+t] = v; }
    c[t] = mybase;
    __syncthreads();
    for(int e=base+t; e<base+cnt; e+=256){
      ull pr = dstbin[e];
      int d = (int)(pr>>32);
      int p = atomicAdd(&c[d-node0],1);
      csr[p] = (int)(pr & 0xffffffffu);
    }
  }
  __syncthreads();
  {
    int base = b*BCAP, cnt = srcCur[b]-base;
    c[t]=0; __syncthreads();
    for(int e=base+t; e<base+cnt; e+=256)
      atomicAdd(&c[srcbin[e]-node0],1);
    __syncthreads();
    if(t<nodes){ int d = c[t]; dinv[node0+t] = (d>0) ? 1.0/sqrt((double)d) : 0.0; }
  }
}

// ---- K3: fused gemm + reductions + chain + writes (512 thr, 64 nodes/blk) --
__global__ __launch_bounds__(GPT) void k_gemmprep(
    const float* __restrict__ x, const float* __restrict__ W,
    const double* __restrict__ hb, const double* __restrict__ hb2p,
    const float* __restrict__ lww,
    double* __restrict__ xtd, float* __restrict__ xtf,
    float2* __restrict__ pab, int N){
  __shared__ float wf[4096];        // [k4][j][m]: flat k4*256 + j*4 + m (16KB)
  __shared__ float xf[NPB*64];      // [n][k] f32 (16KB)
  int tid = threadIdx.x;
  for(int a=tid; a<4096; a+=GPT){   // linear LDS writes; W gathered from L1
    int j = (a>>2)&63;
    int k = ((a>>8)<<2) | (a&3);
    wf[a] = W[j*64 + k];
  }
  int i0 = blockIdx.x*NPB;
  for(int idx=tid; idx<NPB*64; idx+=GPT){
    int node = i0 + (idx>>6);
    xf[idx] = (node<N) ? x[(size_t)node*64 + (idx&63)] : 0.f;
  }
  __syncthreads();
  int lane = tid & 63;
  int nb = (tid>>6)*8;              // this wave's first node-in-block (8/wave)
  double acc0=0.0, acc1=0.0, acc2=0.0, acc3=0.0;
  double acc4=0.0, acc5=0.0, acc6=0.0, acc7=0.0;
  const float4* wq = (const float4*)wf;   // wq[k4*64 + lane]
  const float4* xq = (const float4*)xf;   // xq[node_local*16 + k4]
#pragma unroll 2
  for(int k4=0; k4<16; ++k4){
    float4 w4 = wq[k4*64 + lane];
    double w0=(double)w4.x, w1=(double)w4.y, w2d=(double)w4.z, w3=(double)w4.w;
#define MAC(n, accn) { float4 v = xq[(nb+(n))*16 + k4];                       \
    accn = fma(w0,(double)v.x,accn); accn = fma(w1,(double)v.y,accn);         \
    accn = fma(w2d,(double)v.z,accn); accn = fma(w3,(double)v.w,accn); }
    MAC(0,acc0) MAC(1,acc1) MAC(2,acc2) MAC(3,acc3)
    MAC(4,acc4) MAC(5,acc5) MAC(6,acc6) MAC(7,acc7)
#undef MAC
  }
  double hbl = hb[lane];
  double y2 = *hb2p;
  float wAl = lww[lane], wBl = lww[64+lane];
  // ---- two batches of 4 nodes: reductions + chain (lanes 0-3) + emit ------
#define EMIT(node, accn, aln, ben) { int nd=(node); if(nd<N){                 \
    double v = (aln)*(accn) + (ben)*hbl;                                      \
    xtd[(size_t)nd*64+lane] = v;                                              \
    float vf = (float)v;                                                      \
    xtf[(size_t)nd*64+lane] = vf;                                             \
    float pA = wsumf(vf*wAl);                                                 \
    float pB = wsumf(vf*wBl);                                                 \
    if(lane==0) pab[nd] = make_float2(pA,pB); } }
#define BATCH(A0,A1,A2,A3, OFF) {                                             \
    double xd0 = (double)xf[(nb+(OFF)+0)*64+lane];                            \
    double xd1 = (double)xf[(nb+(OFF)+1)*64+lane];                            \
    double xd2 = (double)xf[(nb+(OFF)+2)*64+lane];                            \
    double xd3 = (double)xf[(nb+(OFF)+3)*64+lane];                            \
    double s1_0 = wsumd(xd0*xd0), s2_0 = wsumd((A0)*(A0)), s3_0 = wsumd((A0)*hbl); \
    double s1_1 = wsumd(xd1*xd1), s2_1 = wsumd((A1)*(A1)), s3_1 = wsumd((A1)*hbl); \
    double s1_2 = wsumd(xd2*xd2), s2_2 = wsumd((A2)*(A2)), s3_2 = wsumd((A2)*hbl); \
    double s1_3 = wsumd(xd3*xd3), s2_3 = wsumd((A3)*(A3)), s3_3 = wsumd((A3)*hbl); \
    int r = lane & 3;                                                         \
    double x2s = (r==0)?s1_0:(r==1)?s1_1:(r==2)?s1_2:s1_3;                    \
    double m2  = (r==0)?s2_0:(r==1)?s2_1:(r==2)?s2_2:s2_3;                    \
    double mh  = (r==0)?s3_0:(r==1)?s3_1:(r==2)?s3_2:s3_3;                    \
    double xn  = fmax(sqrt(x2s), 1e-15);                                      \
    double mxn = fmax(sqrt(m2), 1e-15);                                       \
    double xc  = fmin(fmax(xn, -1.0+1e-7), 1.0-1e-7);                         \
    double at  = 0.5*(log1p(xc)-log1p(-xc));                                  \
    double f1  = tanh(mxn/xn*at)/mxn;                                         \
    if(m2 == 0.0) f1 = 0.0;                                                   \
    double h2 = f1*f1*m2;                                                     \
    double hn = fmax(sqrt(h2), 1e-15);                                        \
    if(hn > MAXN_D){ double s = MAXN_D/hn; f1 *= s; h2 = f1*f1*m2; }          \
    double xy = f1*mh;                                                        \
    double den = fmax(1.0 + 2.0*xy + h2*y2, 1e-15);                           \
    double a = (1.0 + 2.0*xy + y2)/den;                                       \
    double bb = (1.0 - h2)/den;                                               \
    double p2 = a*a*h2 + 2.0*a*bb*xy + bb*bb*y2;                              \
    double pn = fmax(sqrt(p2), 1e-15);                                        \
    if(pn > MAXN_D){ double s = MAXN_D/pn; a*=s; bb*=s; pn = fmax(pn*s, 1e-15); } \
    double nc  = fmin(fmax(pn, -1.0+1e-7), 1.0-1e-7);                         \
    double at2 = 0.5*(log1p(nc)-log1p(-nc));                                  \
    double sc  = at2/pn;                                                      \
    double al = sc*a*f1, be = sc*bb;                                          \
    double al0=__shfl(al,0,64), be0=__shfl(be,0,64);                          \
    double al1=__shfl(al,1,64), be1=__shfl(be,1,64);                          \
    double al2=__shfl(al,2,64), be2=__shfl(be,2,64);                          \
    double al3=__shfl(al,3,64), be3=__shfl(be,3,64);                          \
    EMIT(i0+nb+(OFF)+0, A0, al0, be0)                                         \
    EMIT(i0+nb+(OFF)+1, A1, al1, be1)                                         \
    EMIT(i0+nb+(OFF)+2, A2, al2, be2)                                         \
    EMIT(i0+nb+(OFF)+3, A3, al3, be3)                                         \
  }
  BATCH(acc0,acc1,acc2,acc3, 0)
  BATCH(acc4,acc5,acc6,acc7, 4)
#undef BATCH
#undef EMIT
}

// ---- K4: gather A: info score key (f64 accum over f32 rows) ----------------
__global__ void k_gatherA(const int* __restrict__ csr, const int* __restrict__ rowbeg,
                          const int* __restrict__ rowcnt,
                          const float* __restrict__ xtf, const double* __restrict__ xtd,
                          const double* __restrict__ dinv,
                          ull* __restrict__ keys, int N){
  int lane = threadIdx.x & 63;
  int i = (int)((blockIdx.x*(unsigned)blockDim.x + threadIdx.x)>>6);
  if(i>=N) return;
  int beg = rowbeg[i], deg = rowcnt[i];
  int g = lane>>4, t = lane&15;
  double di = dinv[i];
  double a0=0.0,a1=0.0,a2=0.0,a3=0.0;
  int j = g;
  int s = (j<deg) ? csr[beg+j] : 0;
  while(j < deg){
    int snext = (j+4<deg) ? csr[beg+j+4] : 0;       // prefetch next index
    if(s != i){
      double w = di*dinv[s];
      float4 v = *((const float4*)(xtf + (size_t)s*64 + t*4));
      a0 -= w*(double)v.x; a1 -= w*(double)v.y;
      a2 -= w*(double)v.z; a3 -= w*(double)v.w;
    }
    s = snext; j += 4;
  }
  a0 = gsumd(a0); a1 = gsumd(a1); a2 = gsumd(a2); a3 = gsumd(a3);
  const double2* xr = (const double2*)(xtd + (size_t)i*64 + t*4);
  double2 x0 = xr[0], x1 = xr[1];
  double sc = fabs(x0.x+a0) + fabs(x0.y+a1) + fabs(x1.x+a2) + fabs(x1.y+a3);
  sc = qsumd(sc);
  if(lane==0) keys[i] = (ull)__double_as_longlong(sc);
}

// ---- K5: one 13-bit radix level: LDS hist + global merge + ticketed pick ---
__global__ __launch_bounds__(256) void k_sel13(
    const ull* __restrict__ keys, int N,
    ull* __restrict__ pref, int* __restrict__ rem,
    int lev, int shift, int width,
    int* __restrict__ hist /*SBIN, zeroed*/, int* __restrict__ ticket){
  __shared__ int h[SBIN];
  __shared__ int part[256];
  __shared__ int lastflag, pickedD, pickedR;
  int t = threadIdx.x;
  for(int b=t; b<SBIN; b+=256) h[b] = 0;
  __syncthreads();
  ull p0 = *pref;
  int rem0 = *rem;
  int mask = (1<<width) - 1;
  for(int i = blockIdx.x*256 + t; i<N; i += SELB*256){
    ull kk = keys[i];
    if(lev==0 || (kk >> (shift+width)) == (p0 >> (shift+width)))
      atomicAdd(&h[(int)((kk>>shift)&mask)], 1);
  }
  __syncthreads();
  for(int b=t; b<SBIN; b+=256)
    if(h[b]) __hip_atomic_fetch_add(&hist[b], h[b],
                                    __ATOMIC_RELAXED, __HIP_MEMORY_SCOPE_AGENT);
  __threadfence();
  if(t==0){
    int tk = __hip_atomic_fetch_add(ticket, 1, __ATOMIC_ACQ_REL, __HIP_MEMORY_SCOPE_AGENT);
    lastflag = (tk == SELB-1);
  }
  __syncthreads();
  if(!lastflag) return;
  // last block: descending chunked scan of global hist
  int base = SBIN-1 - 32*t;               // this thread's chunk: base .. base-31
  int pt = 0;
  for(int m=0;m<32;m++)
    pt += __hip_atomic_load(&hist[base-m], __ATOMIC_RELAXED, __HIP_MEMORY_SCOPE_AGENT);
  part[t] = pt;
  __syncthreads();
  for(int off=1; off<256; off<<=1){
    int a = (t>=off) ? part[t-off] : 0; __syncthreads();
    part[t] += a; __syncthreads();
  }
  int cumt = part[t];
  int prev = (t==0) ? 0 : part[t-1];
  if(cumt >= rem0 && prev < rem0){
    int c = 0;
    for(int m=0;m<32;m++){
      int hv = __hip_atomic_load(&hist[base-m], __ATOMIC_RELAXED, __HIP_MEMORY_SCOPE_AGENT);
      c += hv;
      if(prev + c >= rem0){ pickedD = base-m; pickedR = rem0 - (prev + c - hv); break; }
    }
  }
  __syncthreads();
  if(t==0){
    *rem = pickedR;
    *pref = p0 | ((ull)pickedD << shift);
  }
}

// ---- K6: finish: compact 26-bit-prefix candidates, exact rank-select -------
__global__ __launch_bounds__(256) void k_finish(
    const ull* __restrict__ keys, int N,
    ull* __restrict__ pref, const int* __restrict__ rem,
    ull* __restrict__ cand, int* __restrict__ cnt, int* __restrict__ ticket){
  __shared__ ull sc[4096];
  __shared__ int lastflag;
  __shared__ ull winner;
  int t = threadIdx.x;
  ull p0 = *pref;                          // bits 63..38 fixed, low bits 0
  for(int i = blockIdx.x*256 + t; i<N; i += SELB*256){
    ull kk = keys[i];
    if((kk>>38) == (p0>>38)){
      int idx = __hip_atomic_fetch_add(cnt, 1, __ATOMIC_RELAXED, __HIP_MEMORY_SCOPE_AGENT);
      if(idx < CAND_CAP)
        __hip_atomic_store(&cand[idx], kk, __ATOMIC_RELAXED, __HIP_MEMORY_SCOPE_AGENT);
    }
  }
  __threadfence();
  __syncthreads();
  if(t==0){
    int tk = __hip_atomic_fetch_add(ticket, 1, __ATOMIC_ACQ_REL, __HIP_MEMORY_SCOPE_AGENT);
    lastflag = (tk == SELB-1);
  }
  __syncthreads();
  if(!lastflag) return;
  int C = __hip_atomic_load(cnt, __ATOMIC_RELAXED, __HIP_MEMORY_SCOPE_AGENT);
  if(C > 4096) C = 4096;                   // expected C ~ 12; cap is ~10^3 sigma
  for(int j=t; j<C; j+=256)
    sc[j] = __hip_atomic_load(&cand[j], __ATOMIC_RELAXED, __HIP_MEMORY_SCOPE_AGENT);
  __syncthreads();
  int r = *rem;                            // rank within prefix group (1-based)
  for(int j=t; j<C; j+=256){
    ull c = sc[j];
    int gt=0, eq=0;
    for(int m=0;m<C;m++){ ull o = sc[m]; gt += (o>c); eq += (o==c); }
    if(gt <= r-1 && r-1 < gt+eq) winner = c;
  }
  __syncthreads();
  if(t==0) *pref = winner;                 // full exact k-th largest key
}

// ---- K7: q[i] = pB + sel*pA (per-source gate contribution) -----------------
__global__ void k_qval(const float2* __restrict__ pab, const ull* __restrict__ keys,
                       const ull* __restrict__ pref, float* __restrict__ q, int N){
  int i = blockIdx.x*blockDim.x + threadIdx.x;
  if(i>=N) return;
  float2 p = pab[i];
  q[i] = p.y + ((keys[i] > *pref) ? p.x : 0.f);
}

// ---- K8: gather C: z = sum q[src]; gg = sel * sigmoid(z+b) -----------------
__global__ void k_gatherC(const int* __restrict__ csr, const int* __restrict__ rowbeg,
                          const int* __restrict__ rowcnt,
                          const float* __restrict__ q,
                          const ull* __restrict__ keys, const ull* __restrict__ pref,
                          const float* __restrict__ lwb,
                          float* __restrict__ gg, int N){
  int lane = threadIdx.x & 63;
  int wid  = (int)((blockIdx.x*(unsigned)blockDim.x + threadIdx.x)>>6);
  int g = lane>>4, t = lane&15;
  int i = wid*4 + g;
  if(i>=N) return;
  int beg = rowbeg[i], end = beg + rowcnt[i];
  float z = 0.f;
  for(int e = beg + t; e < end; e += 16) z += q[csr[e]];
  z = qsumf(z);
  if(t==0){
    float gv = 1.f/(1.f+expf(-(z + lwb[0])));
    gg[i] = (keys[i] > *pref) ? gv : 0.f;
  }
}

// ---- K9: gather D + final chain (gg-gated row gather) ----------------------
__global__ void k_gatherD(const int* __restrict__ csr, const int* __restrict__ rowbeg,
                          const int* __restrict__ rowcnt,
                          const float* __restrict__ xtf, const float* __restrict__ gg,
                          float* __restrict__ out, int N){
  int lane = threadIdx.x & 63;
  int i = (int)((blockIdx.x*(unsigned)blockDim.x + threadIdx.x)>>6);
  if(i>=N) return;
  int beg = rowbeg[i], deg = rowcnt[i];
  int g = lane>>4, t = lane&15;
  float c0=0.f,c1=0.f,c2=0.f,c3=0.f;
  int j = g;
  int s = (j<deg) ? csr[beg+j] : 0;
  while(j < deg){
    int snext = (j+4<deg) ? csr[beg+j+4] : 0;
    float gv = gg[s];
    if(gv != 0.f){
      float4 v = *((const float4*)(xtf + (size_t)s*64 + t*4));
      c0 = fmaf(gv, v.x, c0); c1 = fmaf(gv, v.y, c1);
      c2 = fmaf(gv, v.z, c2); c3 = fmaf(gv, v.w, c3);
    }
    s = snext; j += 4;
  }
  c0 = gsumf(c0); c1 = gsumf(c1); c2 = gsumf(c2); c3 = gsumf(c3);
  float4 xr = *((const float4*)(xtf + (size_t)i*64 + t*4));
  float v0 = xr.x + fmaxf(c0,0.f);
  float v1 = xr.y + fmaxf(c1,0.f);
  float v2 = xr.z + fmaxf(c2,0.f);
  float v3 = xr.w + fmaxf(c3,0.f);
  float n2 = qsumf(v0*v0 + v1*v1 + v2*v2 + v3*v3);
  float n = fmaxf(sqrtf(n2), 1e-15f);
  float f = tanhf(n)/n;
  float e0=f*v0, e1=f*v1, e2=f*v2, e3=f*v3;
  float en = fmaxf(tanhf(n), 1e-15f);
  if(en > MAXN_F){ float sf = MAXN_F/en; e0*=sf; e1*=sf; e2*=sf; e3*=sf; }
  e0 = fmaxf(e0,0.f); e1 = fmaxf(e1,0.f); e2 = fmaxf(e2,0.f); e3 = fmaxf(e3,0.f);
  float m2 = qsumf(e0*e0 + e1*e1 + e2*e2 + e3*e3);
  float nb = fmaxf(sqrtf(m2), 1e-15f);
  float f2 = tanhf(nb)/nb;
  float o0=f2*e0, o1=f2*e1, o2=f2*e2, o3=f2*e3;
  float on = fmaxf(tanhf(nb), 1e-15f);
  if(on > MAXN_F){ float sf = MAXN_F/on; o0*=sf; o1*=sf; o2*=sf; o3*=sf; }
  if(g==0){
    float4 ov = make_float4(o0,o1,o2,o3);
    *((float4*)(out + (size_t)i*64 + t*4)) = ov;
  }
}

// ---------------------------------------------------------------------------
extern "C" void kernel_launch(void* const* d_in, const int* in_sizes, int n_in,
                              void* d_out, int out_size, void* d_ws, size_t ws_size,
                              hipStream_t stream){
  const float* x    = (const float*)d_in[0];
  const int*   ei   = (const int*)d_in[1];
  const float* W    = (const float*)d_in[2];
  const float* bias = (const float*)d_in[3];
  const float* lww  = (const float*)d_in[4];
  const float* lwb  = (const float*)d_in[5];
  int N = in_sizes[0]/64;
  int E = in_sizes[1]/2;
  int kth = (int)((double)N*0.75);
  int NB = (N+255)>>8;                         // node buckets (256 nodes each)
  if(NB > NBMAX) return;                       // loud failure if N too large
  long long meanPB = (long long)E / (NB > 0 ? NB : 1);
  if(3*meanPB > 2*(long long)BCAP) return;     // require BCAP >= 1.5x mean
  int chunk = (E + BINBLK - 1)/BINBLK;
  size_t binEls = (size_t)NB*BCAP + 4096;      // +slack (OOB insurance)

  char* ws = (char*)d_ws;
  size_t cur = 0;
  auto alloc = [&](size_t bytes){ size_t o = cur; cur = (cur + bytes + 255) & ~(size_t)255; return o; };
  size_t o_hb   = alloc(64*sizeof(double));
  size_t o_hb2  = alloc(8);
  size_t o_rem  = alloc(4);
  size_t o_zero = cur;                         // ---- zeroed region start ----
  size_t o_pref = alloc(8);                    // radix prefix (must start 0)
  size_t o_hist = alloc(2*(size_t)SBIN*4);     // per-level 13-bit hist
  size_t o_tick = alloc(3*4);                  // lev0, lev1, finish tickets
  size_t o_cnt  = alloc(4);                    // candidate count
  size_t zlen   = cur - o_zero;                // ---- zeroed region end ------
  size_t o_cand = alloc((size_t)CAND_CAP*8);
  size_t o_dCur = alloc((size_t)NBMAX*4);
  size_t o_sCur = alloc((size_t)NBMAX*4);
  size_t o_rbeg = alloc((size_t)N*4);
  size_t o_rcnt = alloc((size_t)N*4);
  size_t o_csr  = alloc(binEls*4);
  size_t o_dbin = alloc(binEls*8);
  size_t o_sbin = alloc(binEls*4);
  size_t o_dinv = alloc((size_t)N*8);
  size_t o_keys = alloc((size_t)N*8);
  size_t o_pab  = alloc((size_t)N*8);
  size_t o_q    = alloc((size_t)N*4);
  size_t o_xtf  = alloc((size_t)N*64*4);
  size_t o_xtd  = alloc((size_t)N*64*8);
  size_t o_gg   = alloc((size_t)N*4);
  if(ws_size < cur) return;                    // loud, clean failure

  double* hb     = (double*)(ws+o_hb);
  double* hb2    = (double*)(ws+o_hb2);
  int*    rem    = (int*)(ws+o_rem);
  ull*    pref   = (ull*)(ws+o_pref);
  int*    hist   = (int*)(ws+o_hist);
  int*    tick   = (int*)(ws+o_tick);
  int*    cnt    = (int*)(ws+o_cnt);
  ull*    cand   = (ull*)(ws+o_cand);
  int*    dstCur = (int*)(ws+o_dCur);
  int*    srcCur = (int*)(ws+o_sCur);
  int*    rowbeg = (int*)(ws+o_rbeg);
  int*    rowcnt = (int*)(ws+o_rcnt);
  int*    csr    = (int*)(ws+o_csr);
  ull*    dstbin = (ull*)(ws+o_dbin);
  int*    srcbin = (int*)(ws+o_sbin);
  double* dinv   = (double*)(ws+o_dinv);
  ull*    keys   = (ull*)(ws+o_keys);
  float2* pab    = (float2*)(ws+o_pab);
  float*  q      = (float*)(ws+o_q);
  float*  xtf    = (float*)(ws+o_xtf);
  double* xtd    = (double*)(ws+o_xtd);
  float*  gg     = (float*)(ws+o_gg);

  hipMemsetAsync(ws+o_zero, 0, zlen, stream);

  int nodeBlocks = (N+3)/4;                    // 1 wave per node
  int pBlocks    = (N+15)/16;                  // 4 nodes per wave

  k_init     <<<1, 256, 0, stream>>>(bias, hb, hb2, rem, kth, dstCur, srcCur, NB);
  k_binPlace <<<BINBLK, 256, 0, stream>>>(ei, E, NB, chunk, dstCur, srcCur, dstbin, srcbin);
  k_bucketAB <<<NB, 256, 0, stream>>>(dstbin, dstCur, rowbeg, rowcnt, csr,
                                      srcbin, srcCur, dinv, N);
  k_gemmprep <<<(N+NPB-1)/NPB, GPT, 0, stream>>>(x, W, hb, hb2, lww, xtd, xtf, pab, N);
  k_gatherA  <<<nodeBlocks, 256, 0, stream>>>(csr, rowbeg, rowcnt, xtf, xtd, dinv, keys, N);
  k_sel13    <<<SELB, 256, 0, stream>>>(keys, N, pref, rem, 0, 51, 13, hist, tick+0);
  k_sel13    <<<SELB, 256, 0, stream>>>(keys, N, pref, rem, 1, 38, 13, hist+SBIN, tick+1);
  k_finish   <<<SELB, 256, 0, stream>>>(keys, N, pref, rem, cand, cnt, tick+2);
  k_qval     <<<(N+255)/256, 256, 0, stream>>>(pab, keys, pref, q, N);
  k_gatherC  <<<pBlocks, 256, 0, stream>>>(csr, rowbeg, rowcnt, q, keys, pref, lwb, gg, N);
  k_gatherD  <<<nodeBlocks, 256, 0, stream>>>(csr, rowbeg, rowcnt, xtf, gg, (float*)d_out, N);
}

// Round 17
// 353.385 us; speedup vs baseline: 1.0315x; 1.0315x over previous
//
#include <hip/hip_runtime.h>
#include <math.h>

// ---------------------------------------------------------------------------
// HyperbolicGraphConvolution (HGCN HypLinear + NodeSelect + HypAct), c=1.
// Round 17: chain-dedup in gemmprep. R16 showed the kernel invariant at
// ~126us across occupancy configs -> issue-bound; the f64 transcendental
// chain ran once per 4-node BATCH (25k wave-executions). Now: reductions ->
// LDS, wave 0 runs the chain ONCE for all 64 block nodes (lane=node, 1563
// executions, 16x cut), alpha/beta via LDS, all waves emit. Outputs
// bit-identical (same r-values, same formula). Rest identical to R16.
// ---------------------------------------------------------------------------

#define MAXN_D 0.996      // (1 - 4e-3)/sqrt(c), c=1
#define MAXN_F 0.996f
#define NPB 64            // nodes per block in k_gemmprep (8 per wave, 8 waves)
#define GPT 512           // gemmprep threads per block
#define NBMAX 512         // max buckets (N <= 131072)
#define BCAP 6144         // static bucket capacity (mean 3072, sigma 55)
#define BINBLK 256        // blocks in bin kernels
#define SELB 128          // blocks per select level
#define SBIN 8192         // 13-bit radix bins
#define CAND_CAP 16384    // finish-stage candidate cap (expect ~12)

typedef unsigned long long ull;

__device__ __forceinline__ double wsumd(double v){
#pragma unroll
  for(int o=32;o;o>>=1) v += __shfl_xor(v,o,64);
  return v;
}
__device__ __forceinline__ float wsumf(float v){
#pragma unroll
  for(int o=32;o;o>>=1) v += __shfl_xor(v,o,64);
  return v;
}
__device__ __forceinline__ double qsumd(double v){
#pragma unroll
  for(int o=1;o<16;o<<=1) v += __shfl_xor(v,o,64);
  return v;
}
__device__ __forceinline__ float qsumf(float v){
#pragma unroll
  for(int o=1;o<16;o<<=1) v += __shfl_xor(v,o,64);
  return v;
}
__device__ __forceinline__ double gsumd(double v){
  v += __shfl_xor(v,16,64); v += __shfl_xor(v,32,64); return v;
}
__device__ __forceinline__ float gsumf(float v){
  v += __shfl_xor(v,16,64); v += __shfl_xor(v,32,64); return v;
}

// ---- K0: hyp_bias (double) + |hb|^2 + rem + static bucket cursors ----------
__global__ __launch_bounds__(256) void k_init(
    const float* __restrict__ bias, double* __restrict__ hb,
    double* __restrict__ hb2, int* __restrict__ rem, int kth,
    int* __restrict__ dstCur, int* __restrict__ srcCur, int NB){
  if(threadIdx.x < 64){
    int lane = threadIdx.x;
    double b = (double)bias[lane];
    double n = fmax(sqrt(wsumd(b*b)), 1e-15);
    double e = tanh(n)*b/n;                       // expmap0, sc=1
    double en = fmax(sqrt(wsumd(e*e)), 1e-15);
    if(en > MAXN_D) e *= MAXN_D/en;               // proj
    hb[lane] = e;
    double s2 = wsumd(e*e);
    if(lane==0) *hb2 = s2;
  }
  if(threadIdx.x == 0) *rem = kth;
  for(int b=threadIdx.x; b<NB; b+=256){
    dstCur[b] = b*BCAP;
    srcCur[b] = b*BCAP;
  }
}

// ---- K1: bin place into static-cap regions (line-dense binned writes) ------
__global__ __launch_bounds__(256) void k_binPlace(const int* __restrict__ ei, int E,
    int NB, int chunk, int* __restrict__ dstCur, int* __restrict__ srcCur,
    ull* __restrict__ dstbin, int* __restrict__ srcbin){
  __shared__ int dh[NBMAX], sh_[NBMAX];
  __shared__ int db[NBMAX], sb[NBMAX];
  for(int t=threadIdx.x; t<NB; t+=256){ dh[t]=0; sh_[t]=0; }
  __syncthreads();
  int start = blockIdx.x*chunk, end = min(E, start+chunk);
  for(int e=start+(int)threadIdx.x; e<end; e+=256){
    int s = ei[e], d = ei[(size_t)E+e];
    atomicAdd(&dh[d>>8],1);
    if(s!=d) atomicAdd(&sh_[s>>8],1);
  }
  __syncthreads();
  for(int t=threadIdx.x; t<NB; t+=256){
    db[t] = dh[t]  ? atomicAdd(&dstCur[t], dh[t])  : 0;
    sb[t] = sh_[t] ? atomicAdd(&srcCur[t], sh_[t]) : 0;
  }
  __syncthreads();
  for(int t=threadIdx.x; t<NB; t+=256){ dh[t]=db[t]; sh_[t]=sb[t]; }
  __syncthreads();
  for(int e=start+(int)threadIdx.x; e<end; e+=256){
    int s = ei[e], d = ei[(size_t)E+e];
    int p = atomicAdd(&dh[d>>8],1);
    dstbin[p] = ((ull)(unsigned)d<<32) | (unsigned)s;
    if(s!=d){ int p2 = atomicAdd(&sh_[s>>8],1); srcbin[p2] = s; }
  }
}

// ---- K2: per bucket: dst->rowbeg/rowcnt/csr, then src->dinv ----------------
__global__ __launch_bounds__(256) void k_bucketAB(
    const ull* __restrict__ dstbin, const int* __restrict__ dstCur,
    int* __restrict__ rowbeg, int* __restrict__ rowcnt, int* __restrict__ csr,
    const int* __restrict__ srcbin, const int* __restrict__ srcCur,
    double* __restrict__ dinv, int N){
  int b = blockIdx.x;
  int node0 = b<<8;
  int nodes = min(256, N-node0);
  __shared__ int c[256], ex[256];
  int t = threadIdx.x;
  {
    int base = b*BCAP, cnt = dstCur[b]-base;
    c[t]=0; __syncthreads();
    for(int e=base+t; e<base+cnt; e+=256){
      int d = (int)(dstbin[e]>>32);
      atomicAdd(&c[d-node0],1);
    }
    __syncthreads();
    int v = c[t]; ex[t]=v; __syncthreads();
    for(int off=1; off<256; off<<=1){
      int a = (t>=off) ? ex[t-off] : 0; __syncthreads();
      ex[t] += a; __syncthreads();
    }
    int mybase = base + ex[t] - v;
    if(t<nodes){ rowbeg[node0+t] = mybase; rowcnt[node0+t] = v; }
    c[t] = mybase;
    __syncthreads();
    for(int e=base+t; e<base+cnt; e+=256){
      ull pr = dstbin[e];
      int d = (int)(pr>>32);
      int p = atomicAdd(&c[d-node0],1);
      csr[p] = (int)(pr & 0xffffffffu);
    }
  }
  __syncthreads();
  {
    int base = b*BCAP, cnt = srcCur[b]-base;
    c[t]=0; __syncthreads();
    for(int e=base+t; e<base+cnt; e+=256)
      atomicAdd(&c[srcbin[e]-node0],1);
    __syncthreads();
    if(t<nodes){ int d = c[t]; dinv[node0+t] = (d>0) ? 1.0/sqrt((double)d) : 0.0; }
  }
}

// ---- K3: fused gemm + reductions + block-dedup'd chain + writes ------------
__global__ __launch_bounds__(GPT) void k_gemmprep(
    const float* __restrict__ x, const float* __restrict__ W,
    const double* __restrict__ hb, const double* __restrict__ hb2p,
    const float* __restrict__ lww,
    double* __restrict__ xtd, float* __restrict__ xtf,
    float2* __restrict__ pab, int N){
  __shared__ float wf[4096];        // [k4][j][m]: flat k4*256 + j*4 + m (16KB)
  __shared__ float xf[NPB*64];      // [n][k] f32 (16KB)
  __shared__ double r123[NPB][3];   // per-node reduction triple (1.5KB)
  __shared__ double abuf[NPB][2];   // per-node alpha,beta (1KB)
  int tid = threadIdx.x;
  for(int a=tid; a<4096; a+=GPT){   // linear LDS writes; W gathered from L1
    int j = (a>>2)&63;
    int k = ((a>>8)<<2) | (a&3);
    wf[a] = W[j*64 + k];
  }
  int i0 = blockIdx.x*NPB;
  for(int idx=tid; idx<NPB*64; idx+=GPT){
    int node = i0 + (idx>>6);
    xf[idx] = (node<N) ? x[(size_t)node*64 + (idx&63)] : 0.f;
  }
  __syncthreads();
  int lane = tid & 63;
  int nb = (tid>>6)*8;              // this wave's first node-in-block (8/wave)
  double acc0=0.0, acc1=0.0, acc2=0.0, acc3=0.0;
  double acc4=0.0, acc5=0.0, acc6=0.0, acc7=0.0;
  const float4* wq = (const float4*)wf;   // wq[k4*64 + lane]
  const float4* xq = (const float4*)xf;   // xq[node_local*16 + k4]
#pragma unroll 2
  for(int k4=0; k4<16; ++k4){
    float4 w4 = wq[k4*64 + lane];
    double w0=(double)w4.x, w1=(double)w4.y, w2d=(double)w4.z, w3=(double)w4.w;
#define MAC(n, accn) { float4 v = xq[(nb+(n))*16 + k4];                       \
    accn = fma(w0,(double)v.x,accn); accn = fma(w1,(double)v.y,accn);         \
    accn = fma(w2d,(double)v.z,accn); accn = fma(w3,(double)v.w,accn); }
    MAC(0,acc0) MAC(1,acc1) MAC(2,acc2) MAC(3,acc3)
    MAC(4,acc4) MAC(5,acc5) MAC(6,acc6) MAC(7,acc7)
#undef MAC
  }
  double hbl = hb[lane];
  // ---- reductions for 8 nodes -> r123 LDS (values wave-uniform post-wsumd) -
#define RED4(A0,A1,A2,A3, OFF) {                                              \
    double xd0 = (double)xf[(nb+(OFF)+0)*64+lane];                            \
    double xd1 = (double)xf[(nb+(OFF)+1)*64+lane];                            \
    double xd2 = (double)xf[(nb+(OFF)+2)*64+lane];                            \
    double xd3 = (double)xf[(nb+(OFF)+3)*64+lane];                            \
    double s1_0 = wsumd(xd0*xd0), s2_0 = wsumd((A0)*(A0)), s3_0 = wsumd((A0)*hbl); \
    double s1_1 = wsumd(xd1*xd1), s2_1 = wsumd((A1)*(A1)), s3_1 = wsumd((A1)*hbl); \
    double s1_2 = wsumd(xd2*xd2), s2_2 = wsumd((A2)*(A2)), s3_2 = wsumd((A2)*hbl); \
    double s1_3 = wsumd(xd3*xd3), s2_3 = wsumd((A3)*(A3)), s3_3 = wsumd((A3)*hbl); \
    if(lane==0){                                                              \
      r123[nb+(OFF)+0][0]=s1_0; r123[nb+(OFF)+0][1]=s2_0; r123[nb+(OFF)+0][2]=s3_0; \
      r123[nb+(OFF)+1][0]=s1_1; r123[nb+(OFF)+1][1]=s2_1; r123[nb+(OFF)+1][2]=s3_1; \
      r123[nb+(OFF)+2][0]=s1_2; r123[nb+(OFF)+2][1]=s2_2; r123[nb+(OFF)+2][2]=s3_2; \
      r123[nb+(OFF)+3][0]=s1_3; r123[nb+(OFF)+3][1]=s2_3; r123[nb+(OFF)+3][2]=s3_3; \
    } }
  RED4(acc0,acc1,acc2,acc3, 0)
  RED4(acc4,acc5,acc6,acc7, 4)
#undef RED4
  __syncthreads();
  // ---- chain: wave 0 only, lane = node-in-block (one execution per block) --
  if(tid < 64){
    double x2s = r123[tid][0], m2 = r123[tid][1], mh = r123[tid][2];
    double y2 = *hb2p;
    double xn  = fmax(sqrt(x2s), 1e-15);
    double mxn = fmax(sqrt(m2), 1e-15);
    double xc  = fmin(fmax(xn, -1.0+1e-7), 1.0-1e-7);
    double at  = 0.5*(log1p(xc)-log1p(-xc));        // artanh(|x|)
    double f1  = tanh(mxn/xn*at)/mxn;               // h = f1*mx
    if(m2 == 0.0) f1 = 0.0;
    double h2 = f1*f1*m2;
    double hn = fmax(sqrt(h2), 1e-15);
    if(hn > MAXN_D){ double s = MAXN_D/hn; f1 *= s; h2 = f1*f1*m2; }   // proj(h)
    double xy = f1*mh;
    double den = fmax(1.0 + 2.0*xy + h2*y2, 1e-15);
    double a = (1.0 + 2.0*xy + y2)/den;
    double bb = (1.0 - h2)/den;
    double p2 = a*a*h2 + 2.0*a*bb*xy + bb*bb*y2;
    double pn = fmax(sqrt(p2), 1e-15);
    if(pn > MAXN_D){ double s = MAXN_D/pn; a*=s; bb*=s; pn = fmax(pn*s, 1e-15); }
    double nc  = fmin(fmax(pn, -1.0+1e-7), 1.0-1e-7);
    double at2 = 0.5*(log1p(nc)-log1p(-nc));        // artanh(|p|)
    double sc  = at2/pn;                            // logmap0 scale
    abuf[tid][0] = sc*a*f1;
    abuf[tid][1] = sc*bb;
  }
  __syncthreads();
  // ---- emit (alpha/beta broadcast-read from LDS) ---------------------------
  float wAl = lww[lane], wBl = lww[64+lane];
#define EMIT(n, accn) { int nd=i0+nb+(n); if(nd<N){                           \
    double al = abuf[nb+(n)][0], be = abuf[nb+(n)][1];                        \
    double v = al*(accn) + be*hbl;                                            \
    xtd[(size_t)nd*64+lane] = v;                                              \
    float vf = (float)v;                                                      \
    xtf[(size_t)nd*64+lane] = vf;                                             \
    float pA = wsumf(vf*wAl);                                                 \
    float pB = wsumf(vf*wBl);                                                 \
    if(lane==0) pab[nd] = make_float2(pA,pB); } }
  EMIT(0,acc0) EMIT(1,acc1) EMIT(2,acc2) EMIT(3,acc3)
  EMIT(4,acc4) EMIT(5,acc5) EMIT(6,acc6) EMIT(7,acc7)
#undef EMIT
}

// ---- K4: gather A: info score key (f64 accum over f32 rows) ----------------
__global__ void k_gatherA(const int* __restrict__ csr, const int* __restrict__ rowbeg,
                          const int* __restrict__ rowcnt,
                          const float* __restrict__ xtf, const double* __restrict__ xtd,
                          const double* __restrict__ dinv,
                          ull* __restrict__ keys, int N){
  int lane = threadIdx.x & 63;
  int i = (int)((blockIdx.x*(unsigned)blockDim.x + threadIdx.x)>>6);
  if(i>=N) return;
  int beg = rowbeg[i], deg = rowcnt[i];
  int g = lane>>4, t = lane&15;
  double di = dinv[i];
  double a0=0.0,a1=0.0,a2=0.0,a3=0.0;
  int j = g;
  int s = (j<deg) ? csr[beg+j] : 0;
  while(j < deg){
    int snext = (j+4<deg) ? csr[beg+j+4] : 0;       // prefetch next index
    if(s != i){
      double w = di*dinv[s];
      float4 v = *((const float4*)(xtf + (size_t)s*64 + t*4));
      a0 -= w*(double)v.x; a1 -= w*(double)v.y;
      a2 -= w*(double)v.z; a3 -= w*(double)v.w;
    }
    s = snext; j += 4;
  }
  a0 = gsumd(a0); a1 = gsumd(a1); a2 = gsumd(a2); a3 = gsumd(a3);
  const double2* xr = (const double2*)(xtd + (size_t)i*64 + t*4);
  double2 x0 = xr[0], x1 = xr[1];
  double sc = fabs(x0.x+a0) + fabs(x0.y+a1) + fabs(x1.x+a2) + fabs(x1.y+a3);
  sc = qsumd(sc);
  if(lane==0) keys[i] = (ull)__double_as_longlong(sc);
}

// ---- K5: one 13-bit radix level: LDS hist + global merge + ticketed pick ---
__global__ __launch_bounds__(256) void k_sel13(
    const ull* __restrict__ keys, int N,
    ull* __restrict__ pref, int* __restrict__ rem,
    int lev, int shift, int width,
    int* __restrict__ hist /*SBIN, zeroed*/, int* __restrict__ ticket){
  __shared__ int h[SBIN];
  __shared__ int part[256];
  __shared__ int lastflag, pickedD, pickedR;
  int t = threadIdx.x;
  for(int b=t; b<SBIN; b+=256) h[b] = 0;
  __syncthreads();
  ull p0 = *pref;
  int rem0 = *rem;
  int mask = (1<<width) - 1;
  for(int i = blockIdx.x*256 + t; i<N; i += SELB*256){
    ull kk = keys[i];
    if(lev==0 || (kk >> (shift+width)) == (p0 >> (shift+width)))
      atomicAdd(&h[(int)((kk>>shift)&mask)], 1);
  }
  __syncthreads();
  for(int b=t; b<SBIN; b+=256)
    if(h[b]) __hip_atomic_fetch_add(&hist[b], h[b],
                                    __ATOMIC_RELAXED, __HIP_MEMORY_SCOPE_AGENT);
  __threadfence();
  if(t==0){
    int tk = __hip_atomic_fetch_add(ticket, 1, __ATOMIC_ACQ_REL, __HIP_MEMORY_SCOPE_AGENT);
    lastflag = (tk == SELB-1);
  }
  __syncthreads();
  if(!lastflag) return;
  // last block: descending chunked scan of global hist
  int base = SBIN-1 - 32*t;               // this thread's chunk: base .. base-31
  int pt = 0;
  for(int m=0;m<32;m++)
    pt += __hip_atomic_load(&hist[base-m], __ATOMIC_RELAXED, __HIP_MEMORY_SCOPE_AGENT);
  part[t] = pt;
  __syncthreads();
  for(int off=1; off<256; off<<=1){
    int a = (t>=off) ? part[t-off] : 0; __syncthreads();
    part[t] += a; __syncthreads();
  }
  int cumt = part[t];
  int prev = (t==0) ? 0 : part[t-1];
  if(cumt >= rem0 && prev < rem0){
    int c = 0;
    for(int m=0;m<32;m++){
      int hv = __hip_atomic_load(&hist[base-m], __ATOMIC_RELAXED, __HIP_MEMORY_SCOPE_AGENT);
      c += hv;
      if(prev + c >= rem0){ pickedD = base-m; pickedR = rem0 - (prev + c - hv); break; }
    }
  }
  __syncthreads();
  if(t==0){
    *rem = pickedR;
    *pref = p0 | ((ull)pickedD << shift);
  }
}

// ---- K6: finish: compact 26-bit-prefix candidates, exact rank-select -------
__global__ __launch_bounds__(256) void k_finish(
    const ull* __restrict__ keys, int N,
    ull* __restrict__ pref, const int* __restrict__ rem,
    ull* __restrict__ cand, int* __restrict__ cnt, int* __restrict__ ticket){
  __shared__ ull sc[4096];
  __shared__ int lastflag;
  __shared__ ull winner;
  int t = threadIdx.x;
  ull p0 = *pref;                          // bits 63..38 fixed, low bits 0
  for(int i = blockIdx.x*256 + t; i<N; i += SELB*256){
    ull kk = keys[i];
    if((kk>>38) == (p0>>38)){
      int idx = __hip_atomic_fetch_add(cnt, 1, __ATOMIC_RELAXED, __HIP_MEMORY_SCOPE_AGENT);
      if(idx < CAND_CAP)
        __hip_atomic_store(&cand[idx], kk, __ATOMIC_RELAXED, __HIP_MEMORY_SCOPE_AGENT);
    }
  }
  __threadfence();
  __syncthreads();
  if(t==0){
    int tk = __hip_atomic_fetch_add(ticket, 1, __ATOMIC_ACQ_REL, __HIP_MEMORY_SCOPE_AGENT);
    lastflag = (tk == SELB-1);
  }
  __syncthreads();
  if(!lastflag) return;
  int C = __hip_atomic_load(cnt, __ATOMIC_RELAXED, __HIP_MEMORY_SCOPE_AGENT);
  if(C > 4096) C = 4096;                   // expected C ~ 12; cap is ~10^3 sigma
  for(int j=t; j<C; j+=256)
    sc[j] = __hip_atomic_load(&cand[j], __ATOMIC_RELAXED, __HIP_MEMORY_SCOPE_AGENT);
  __syncthreads();
  int r = *rem;                            // rank within prefix group (1-based)
  for(int j=t; j<C; j+=256){
    ull c = sc[j];
    int gt=0, eq=0;
    for(int m=0;m<C;m++){ ull o = sc[m]; gt += (o>c); eq += (o==c); }
    if(gt <= r-1 && r-1 < gt+eq) winner = c;
  }
  __syncthreads();
  if(t==0) *pref = winner;                 // full exact k-th largest key
}

// ---- K7: q[i] = pB + sel*pA (per-source gate contribution) -----------------
__global__ void k_qval(const float2* __restrict__ pab, const ull* __restrict__ keys,
                       const ull* __restrict__ pref, float* __restrict__ q, int N){
  int i = blockIdx.x*blockDim.x + threadIdx.x;
  if(i>=N) return;
  float2 p = pab[i];
  q[i] = p.y + ((keys[i] > *pref) ? p.x : 0.f);
}

// ---- K8: gather C: z = sum q[src]; gg = sel * sigmoid(z+b) -----------------
__global__ void k_gatherC(const int* __restrict__ csr, const int* __restrict__ rowbeg,
                          const int* __restrict__ rowcnt,
                          const float* __restrict__ q,
                          const ull* __restrict__ keys, const ull* __restrict__ pref,
                          const float* __restrict__ lwb,
                          float* __restrict__ gg, int N){
  int lane = threadIdx.x & 63;
  int wid  = (int)((blockIdx.x*(unsigned)blockDim.x + threadIdx.x)>>6);
  int g = lane>>4, t = lane&15;
  int i = wid*4 + g;
  if(i>=N) return;
  int beg = rowbeg[i], end = beg + rowcnt[i];
  float z = 0.f;
  for(int e = beg + t; e < end; e += 16) z += q[csr[e]];
  z = qsumf(z);
  if(t==0){
    float gv = 1.f/(1.f+expf(-(z + lwb[0])));
    gg[i] = (keys[i] > *pref) ? gv : 0.f;
  }
}

// ---- K9: gather D + final chain (gg-gated row gather) ----------------------
__global__ void k_gatherD(const int* __restrict__ csr, const int* __restrict__ rowbeg,
                          const int* __restrict__ rowcnt,
                          const float* __restrict__ xtf, const float* __restrict__ gg,
                          float* __restrict__ out, int N){
  int lane = threadIdx.x & 63;
  int i = (int)((blockIdx.x*(unsigned)blockDim.x + threadIdx.x)>>6);
  if(i>=N) return;
  int beg = rowbeg[i], deg = rowcnt[i];
  int g = lane>>4, t = lane&15;
  float c0=0.f,c1=0.f,c2=0.f,c3=0.f;
  int j = g;
  int s = (j<deg) ? csr[beg+j] : 0;
  while(j < deg){
    int snext = (j+4<deg) ? csr[beg+j+4] : 0;
    float gv = gg[s];
    if(gv != 0.f){
      float4 v = *((const float4*)(xtf + (size_t)s*64 + t*4));
      c0 = fmaf(gv, v.x, c0); c1 = fmaf(gv, v.y, c1);
      c2 = fmaf(gv, v.z, c2); c3 = fmaf(gv, v.w, c3);
    }
    s = snext; j += 4;
  }
  c0 = gsumf(c0); c1 = gsumf(c1); c2 = gsumf(c2); c3 = gsumf(c3);
  float4 xr = *((const float4*)(xtf + (size_t)i*64 + t*4));
  float v0 = xr.x + fmaxf(c0,0.f);
  float v1 = xr.y + fmaxf(c1,0.f);
  float v2 = xr.z + fmaxf(c2,0.f);
  float v3 = xr.w + fmaxf(c3,0.f);
  float n2 = qsumf(v0*v0 + v1*v1 + v2*v2 + v3*v3);
  float n = fmaxf(sqrtf(n2), 1e-15f);
  float f = tanhf(n)/n;
  float e0=f*v0, e1=f*v1, e2=f*v2, e3=f*v3;
  float en = fmaxf(tanhf(n), 1e-15f);
  if(en > MAXN_F){ float sf = MAXN_F/en; e0*=sf; e1*=sf; e2*=sf; e3*=sf; }
  e0 = fmaxf(e0,0.f); e1 = fmaxf(e1,0.f); e2 = fmaxf(e2,0.f); e3 = fmaxf(e3,0.f);
  float m2 = qsumf(e0*e0 + e1*e1 + e2*e2 + e3*e3);
  float nb = fmaxf(sqrtf(m2), 1e-15f);
  float f2 = tanhf(nb)/nb;
  float o0=f2*e0, o1=f2*e1, o2=f2*e2, o3=f2*e3;
  float on = fmaxf(tanhf(nb), 1e-15f);
  if(on > MAXN_F){ float sf = MAXN_F/on; o0*=sf; o1*=sf; o2*=sf; o3*=sf; }
  if(g==0){
    float4 ov = make_float4(o0,o1,o2,o3);
    *((float4*)(out + (size_t)i*64 + t*4)) = ov;
  }
}

// ---------------------------------------------------------------------------
extern "C" void kernel_launch(void* const* d_in, const int* in_sizes, int n_in,
                              void* d_out, int out_size, void* d_ws, size_t ws_size,
                              hipStream_t stream){
  const float* x    = (const float*)d_in[0];
  const int*   ei   = (const int*)d_in[1];
  const float* W    = (const float*)d_in[2];
  const float* bias = (const float*)d_in[3];
  const float* lww  = (const float*)d_in[4];
  const float* lwb  = (const float*)d_in[5];
  int N = in_sizes[0]/64;
  int E = in_sizes[1]/2;
  int kth = (int)((double)N*0.75);
  int NB = (N+255)>>8;                         // node buckets (256 nodes each)
  if(NB > NBMAX) return;                       // loud failure if N too large
  long long meanPB = (long long)E / (NB > 0 ? NB : 1);
  if(3*meanPB > 2*(long long)BCAP) return;     // require BCAP >= 1.5x mean
  int chunk = (E + BINBLK - 1)/BINBLK;
  size_t binEls = (size_t)NB*BCAP + 4096;      // +slack (OOB insurance)

  char* ws = (char*)d_ws;
  size_t cur = 0;
  auto alloc = [&](size_t bytes){ size_t o = cur; cur = (cur + bytes + 255) & ~(size_t)255; return o; };
  size_t o_hb   = alloc(64*sizeof(double));
  size_t o_hb2  = alloc(8);
  size_t o_rem  = alloc(4);
  size_t o_zero = cur;                         // ---- zeroed region start ----
  size_t o_pref = alloc(8);                    // radix prefix (must start 0)
  size_t o_hist = alloc(2*(size_t)SBIN*4);     // per-level 13-bit hist
  size_t o_tick = alloc(3*4);                  // lev0, lev1, finish tickets
  size_t o_cnt  = alloc(4);                    // candidate count
  size_t zlen   = cur - o_zero;                // ---- zeroed region end ------
  size_t o_cand = alloc((size_t)CAND_CAP*8);
  size_t o_dCur = alloc((size_t)NBMAX*4);
  size_t o_sCur = alloc((size_t)NBMAX*4);
  size_t o_rbeg = alloc((size_t)N*4);
  size_t o_rcnt = alloc((size_t)N*4);
  size_t o_csr  = alloc(binEls*4);
  size_t o_dbin = alloc(binEls*8);
  size_t o_sbin = alloc(binEls*4);
  size_t o_dinv = alloc((size_t)N*8);
  size_t o_keys = alloc((size_t)N*8);
  size_t o_pab  = alloc((size_t)N*8);
  size_t o_q    = alloc((size_t)N*4);
  size_t o_xtf  = alloc((size_t)N*64*4);
  size_t o_xtd  = alloc((size_t)N*64*8);
  size_t o_gg   = alloc((size_t)N*4);
  if(ws_size < cur) return;                    // loud, clean failure

  double* hb     = (double*)(ws+o_hb);
  double* hb2    = (double*)(ws+o_hb2);
  int*    rem    = (int*)(ws+o_rem);
  ull*    pref   = (ull*)(ws+o_pref);
  int*    hist   = (int*)(ws+o_hist);
  int*    tick   = (int*)(ws+o_tick);
  int*    cnt    = (int*)(ws+o_cnt);
  ull*    cand   = (ull*)(ws+o_cand);
  int*    dstCur = (int*)(ws+o_dCur);
  int*    srcCur = (int*)(ws+o_sCur);
  int*    rowbeg = (int*)(ws+o_rbeg);
  int*    rowcnt = (int*)(ws+o_rcnt);
  int*    csr    = (int*)(ws+o_csr);
  ull*    dstbin = (ull*)(ws+o_dbin);
  int*    srcbin = (int*)(ws+o_sbin);
  double* dinv   = (double*)(ws+o_dinv);
  ull*    keys   = (ull*)(ws+o_keys);
  float2* pab    = (float2*)(ws+o_pab);
  float*  q      = (float*)(ws+o_q);
  float*  xtf    = (float*)(ws+o_xtf);
  double* xtd    = (double*)(ws+o_xtd);
  float*  gg     = (float*)(ws+o_gg);

  hipMemsetAsync(ws+o_zero, 0, zlen, stream);

  int nodeBlocks = (N+3)/4;                    // 1 wave per node
  int pBlocks    = (N+15)/16;                  // 4 nodes per wave

  k_init     <<<1, 256, 0, stream>>>(bias, hb, hb2, rem, kth, dstCur, srcCur, NB);
  k_binPlace <<<BINBLK, 256, 0, stream>>>(ei, E, NB, chunk, dstCur, srcCur, dstbin, srcbin);
  k_bucketAB <<<NB, 256, 0, stream>>>(dstbin, dstCur, rowbeg, rowcnt, csr,
                                      srcbin, srcCur, dinv, N);
  k_gemmprep <<<(N+NPB-1)/NPB, GPT, 0, stream>>>(x, W, hb, hb2, lww, xtd, xtf, pab, N);
  k_gatherA  <<<nodeBlocks, 256, 0, stream>>>(csr, rowbeg, rowcnt, xtf, xtd, dinv, keys, N);
  k_sel13    <<<SELB, 256, 0, stream>>>(keys, N, pref, rem, 0, 51, 13, hist, tick+0);
  k_sel13    <<<SELB, 256, 0, stream>>>(keys, N, pref, rem, 1, 38, 13, hist+SBIN, tick+1);
  k_finish   <<<SELB, 256, 0, stream>>>(keys, N, pref, rem, cand, cnt, tick+2);
  k_qval     <<<(N+255)/256, 256, 0, stream>>>(pab, keys, pref, q, N);
  k_gatherC  <<<pBlocks, 256, 0, stream>>>(csr, rowbeg, rowcnt, q, keys, pref, lwb, gg, N);
  k_gatherD  <<<nodeBlocks, 256, 0, stream>>>(csr, rowbeg, rowcnt, xtf, gg, (float*)d_out, N);
}

// Round 18
// 338.472 us; speedup vs baseline: 1.0770x; 1.0441x over previous
//
#include <hip/hip_runtime.h>
#include <math.h>

// ---------------------------------------------------------------------------
// HyperbolicGraphConvolution (HGCN HypLinear + NodeSelect + HypAct), c=1.
// Round 18: (1) xtd(f64,51MB) replaced by xdl(f32 delta,26MB): own-row f64
// reconstructed as xtf+xdl (error 4e-18/coord, 1e9x below the 5e-7 order-
// stat gap -> selection set unchanged); (2) gatherA/D at 8 rows in flight
// per wave (8 groups x 8 lanes x 32B), halved per-group chain length.
// Rest identical to R17 (dedup'd chain gemmprep, static-cap CSR, 2x13-bit
// radix + candidate finish).
// ---------------------------------------------------------------------------

#define MAXN_D 0.996      // (1 - 4e-3)/sqrt(c), c=1
#define MAXN_F 0.996f
#define NPB 64            // nodes per block in k_gemmprep (8 per wave, 8 waves)
#define GPT 512           // gemmprep threads per block
#define NBMAX 512         // max buckets (N <= 131072)
#define BCAP 6144         // static bucket capacity (mean 3072, sigma 55)
#define BINBLK 256        // blocks in bin kernels
#define SELB 128          // blocks per select level
#define SBIN 8192         // 13-bit radix bins
#define CAND_CAP 16384    // finish-stage candidate cap (expect ~12)

typedef unsigned long long ull;

__device__ __forceinline__ double wsumd(double v){
#pragma unroll
  for(int o=32;o;o>>=1) v += __shfl_xor(v,o,64);
  return v;
}
__device__ __forceinline__ float wsumf(float v){
#pragma unroll
  for(int o=32;o;o>>=1) v += __shfl_xor(v,o,64);
  return v;
}
__device__ __forceinline__ float qsumf(float v){
#pragma unroll
  for(int o=1;o<16;o<<=1) v += __shfl_xor(v,o,64);
  return v;
}

// ---- K0: hyp_bias (double) + |hb|^2 + rem + static bucket cursors ----------
__global__ __launch_bounds__(256) void k_init(
    const float* __restrict__ bias, double* __restrict__ hb,
    double* __restrict__ hb2, int* __restrict__ rem, int kth,
    int* __restrict__ dstCur, int* __restrict__ srcCur, int NB){
  if(threadIdx.x < 64){
    int lane = threadIdx.x;
    double b = (double)bias[lane];
    double n = fmax(sqrt(wsumd(b*b)), 1e-15);
    double e = tanh(n)*b/n;                       // expmap0, sc=1
    double en = fmax(sqrt(wsumd(e*e)), 1e-15);
    if(en > MAXN_D) e *= MAXN_D/en;               // proj
    hb[lane] = e;
    double s2 = wsumd(e*e);
    if(lane==0) *hb2 = s2;
  }
  if(threadIdx.x == 0) *rem = kth;
  for(int b=threadIdx.x; b<NB; b+=256){
    dstCur[b] = b*BCAP;
    srcCur[b] = b*BCAP;
  }
}

// ---- K1: bin place into static-cap regions (line-dense binned writes) ------
__global__ __launch_bounds__(256) void k_binPlace(const int* __restrict__ ei, int E,
    int NB, int chunk, int* __restrict__ dstCur, int* __restrict__ srcCur,
    ull* __restrict__ dstbin, int* __restrict__ srcbin){
  __shared__ int dh[NBMAX], sh_[NBMAX];
  __shared__ int db[NBMAX], sb[NBMAX];
  for(int t=threadIdx.x; t<NB; t+=256){ dh[t]=0; sh_[t]=0; }
  __syncthreads();
  int start = blockIdx.x*chunk, end = min(E, start+chunk);
  for(int e=start+(int)threadIdx.x; e<end; e+=256){
    int s = ei[e], d = ei[(size_t)E+e];
    atomicAdd(&dh[d>>8],1);
    if(s!=d) atomicAdd(&sh_[s>>8],1);
  }
  __syncthreads();
  for(int t=threadIdx.x; t<NB; t+=256){
    db[t] = dh[t]  ? atomicAdd(&dstCur[t], dh[t])  : 0;
    sb[t] = sh_[t] ? atomicAdd(&srcCur[t], sh_[t]) : 0;
  }
  __syncthreads();
  for(int t=threadIdx.x; t<NB; t+=256){ dh[t]=db[t]; sh_[t]=sb[t]; }
  __syncthreads();
  for(int e=start+(int)threadIdx.x; e<end; e+=256){
    int s = ei[e], d = ei[(size_t)E+e];
    int p = atomicAdd(&dh[d>>8],1);
    dstbin[p] = ((ull)(unsigned)d<<32) | (unsigned)s;
    if(s!=d){ int p2 = atomicAdd(&sh_[s>>8],1); srcbin[p2] = s; }
  }
}

// ---- K2: per bucket: dst->rowbeg/rowcnt/csr, then src->dinv ----------------
__global__ __launch_bounds__(256) void k_bucketAB(
    const ull* __restrict__ dstbin, const int* __restrict__ dstCur,
    int* __restrict__ rowbeg, int* __restrict__ rowcnt, int* __restrict__ csr,
    const int* __restrict__ srcbin, const int* __restrict__ srcCur,
    double* __restrict__ dinv, int N){
  int b = blockIdx.x;
  int node0 = b<<8;
  int nodes = min(256, N-node0);
  __shared__ int c[256], ex[256];
  int t = threadIdx.x;
  {
    int base = b*BCAP, cnt = dstCur[b]-base;
    c[t]=0; __syncthreads();
    for(int e=base+t; e<base+cnt; e+=256){
      int d = (int)(dstbin[e]>>32);
      atomicAdd(&c[d-node0],1);
    }
    __syncthreads();
    int v = c[t]; ex[t]=v; __syncthreads();
    for(int off=1; off<256; off<<=1){
      int a = (t>=off) ? ex[t-off] : 0; __syncthreads();
      ex[t] += a; __syncthreads();
    }
    int mybase = base + ex[t] - v;
    if(t<nodes){ rowbeg[node0+t] = mybase; rowcnt[node0+t] = v; }
    c[t] = mybase;
    __syncthreads();
    for(int e=base+t; e<base+cnt; e+=256){
      ull pr = dstbin[e];
      int d = (int)(pr>>32);
      int p = atomicAdd(&c[d-node0],1);
      csr[p] = (int)(pr & 0xffffffffu);
    }
  }
  __syncthreads();
  {
    int base = b*BCAP, cnt = srcCur[b]-base;
    c[t]=0; __syncthreads();
    for(int e=base+t; e<base+cnt; e+=256)
      atomicAdd(&c[srcbin[e]-node0],1);
    __syncthreads();
    if(t<nodes){ int d = c[t]; dinv[node0+t] = (d>0) ? 1.0/sqrt((double)d) : 0.0; }
  }
}

// ---- K3: fused gemm + reductions + block-dedup'd chain + writes ------------
__global__ __launch_bounds__(GPT) void k_gemmprep(
    const float* __restrict__ x, const float* __restrict__ W,
    const double* __restrict__ hb, const double* __restrict__ hb2p,
    const float* __restrict__ lww,
    float* __restrict__ xtf, float* __restrict__ xdl,
    float2* __restrict__ pab, int N){
  __shared__ float wf[4096];        // [k4][j][m]: flat k4*256 + j*4 + m (16KB)
  __shared__ float xf[NPB*64];      // [n][k] f32 (16KB)
  __shared__ double r123[NPB][3];   // per-node reduction triple (1.5KB)
  __shared__ double abuf[NPB][2];   // per-node alpha,beta (1KB)
  int tid = threadIdx.x;
  for(int a=tid; a<4096; a+=GPT){   // linear LDS writes; W gathered from L1
    int j = (a>>2)&63;
    int k = ((a>>8)<<2) | (a&3);
    wf[a] = W[j*64 + k];
  }
  int i0 = blockIdx.x*NPB;
  for(int idx=tid; idx<NPB*64; idx+=GPT){
    int node = i0 + (idx>>6);
    xf[idx] = (node<N) ? x[(size_t)node*64 + (idx&63)] : 0.f;
  }
  __syncthreads();
  int lane = tid & 63;
  int nb = (tid>>6)*8;              // this wave's first node-in-block (8/wave)
  double acc0=0.0, acc1=0.0, acc2=0.0, acc3=0.0;
  double acc4=0.0, acc5=0.0, acc6=0.0, acc7=0.0;
  const float4* wq = (const float4*)wf;   // wq[k4*64 + lane]
  const float4* xq = (const float4*)xf;   // xq[node_local*16 + k4]
#pragma unroll 2
  for(int k4=0; k4<16; ++k4){
    float4 w4 = wq[k4*64 + lane];
    double w0=(double)w4.x, w1=(double)w4.y, w2d=(double)w4.z, w3=(double)w4.w;
#define MAC(n, accn) { float4 v = xq[(nb+(n))*16 + k4];                       \
    accn = fma(w0,(double)v.x,accn); accn = fma(w1,(double)v.y,accn);         \
    accn = fma(w2d,(double)v.z,accn); accn = fma(w3,(double)v.w,accn); }
    MAC(0,acc0) MAC(1,acc1) MAC(2,acc2) MAC(3,acc3)
    MAC(4,acc4) MAC(5,acc5) MAC(6,acc6) MAC(7,acc7)
#undef MAC
  }
  double hbl = hb[lane];
  // ---- reductions for 8 nodes -> r123 LDS ---------------------------------
#define RED4(A0,A1,A2,A3, OFF) {                                              \
    double xd0 = (double)xf[(nb+(OFF)+0)*64+lane];                            \
    double xd1 = (double)xf[(nb+(OFF)+1)*64+lane];                            \
    double xd2 = (double)xf[(nb+(OFF)+2)*64+lane];                            \
    double xd3 = (double)xf[(nb+(OFF)+3)*64+lane];                            \
    double s1_0 = wsumd(xd0*xd0), s2_0 = wsumd((A0)*(A0)), s3_0 = wsumd((A0)*hbl); \
    double s1_1 = wsumd(xd1*xd1), s2_1 = wsumd((A1)*(A1)), s3_1 = wsumd((A1)*hbl); \
    double s1_2 = wsumd(xd2*xd2), s2_2 = wsumd((A2)*(A2)), s3_2 = wsumd((A2)*hbl); \
    double s1_3 = wsumd(xd3*xd3), s2_3 = wsumd((A3)*(A3)), s3_3 = wsumd((A3)*hbl); \
    if(lane==0){                                                              \
      r123[nb+(OFF)+0][0]=s1_0; r123[nb+(OFF)+0][1]=s2_0; r123[nb+(OFF)+0][2]=s3_0; \
      r123[nb+(OFF)+1][0]=s1_1; r123[nb+(OFF)+1][1]=s2_1; r123[nb+(OFF)+1][2]=s3_1; \
      r123[nb+(OFF)+2][0]=s1_2; r123[nb+(OFF)+2][1]=s2_2; r123[nb+(OFF)+2][2]=s3_2; \
      r123[nb+(OFF)+3][0]=s1_3; r123[nb+(OFF)+3][1]=s2_3; r123[nb+(OFF)+3][2]=s3_3; \
    } }
  RED4(acc0,acc1,acc2,acc3, 0)
  RED4(acc4,acc5,acc6,acc7, 4)
#undef RED4
  __syncthreads();
  // ---- chain: wave 0 only, lane = node-in-block ---------------------------
  if(tid < 64){
    double x2s = r123[tid][0], m2 = r123[tid][1], mh = r123[tid][2];
    double y2 = *hb2p;
    double xn  = fmax(sqrt(x2s), 1e-15);
    double mxn = fmax(sqrt(m2), 1e-15);
    double xc  = fmin(fmax(xn, -1.0+1e-7), 1.0-1e-7);
    double at  = 0.5*(log1p(xc)-log1p(-xc));        // artanh(|x|)
    double f1  = tanh(mxn/xn*at)/mxn;               // h = f1*mx
    if(m2 == 0.0) f1 = 0.0;
    double h2 = f1*f1*m2;
    double hn = fmax(sqrt(h2), 1e-15);
    if(hn > MAXN_D){ double s = MAXN_D/hn; f1 *= s; h2 = f1*f1*m2; }   // proj(h)
    double xy = f1*mh;
    double den = fmax(1.0 + 2.0*xy + h2*y2, 1e-15);
    double a = (1.0 + 2.0*xy + y2)/den;
    double bb = (1.0 - h2)/den;
    double p2 = a*a*h2 + 2.0*a*bb*xy + bb*bb*y2;
    double pn = fmax(sqrt(p2), 1e-15);
    if(pn > MAXN_D){ double s = MAXN_D/pn; a*=s; bb*=s; pn = fmax(pn*s, 1e-15); }
    double nc  = fmin(fmax(pn, -1.0+1e-7), 1.0-1e-7);
    double at2 = 0.5*(log1p(nc)-log1p(-nc));        // artanh(|p|)
    double sc  = at2/pn;                            // logmap0 scale
    abuf[tid][0] = sc*a*f1;
    abuf[tid][1] = sc*bb;
  }
  __syncthreads();
  // ---- emit: xtf + f32 delta (f64 row = xtf + xdl exactly to 4e-18) -------
  float wAl = lww[lane], wBl = lww[64+lane];
#define EMIT(n, accn) { int nd=i0+nb+(n); if(nd<N){                           \
    double al = abuf[nb+(n)][0], be = abuf[nb+(n)][1];                        \
    double v = al*(accn) + be*hbl;                                            \
    float vf = (float)v;                                                      \
    float df = (float)(v - (double)vf);                                       \
    xtf[(size_t)nd*64+lane] = vf;                                             \
    xdl[(size_t)nd*64+lane] = df;                                             \
    float pA = wsumf(vf*wAl);                                                 \
    float pB = wsumf(vf*wBl);                                                 \
    if(lane==0) pab[nd] = make_float2(pA,pB); } }
  EMIT(0,acc0) EMIT(1,acc1) EMIT(2,acc2) EMIT(3,acc3)
  EMIT(4,acc4) EMIT(5,acc5) EMIT(6,acc6) EMIT(7,acc7)
#undef EMIT
}

// ---- K4: gather A: score key, 8 rows in flight (8 groups x 8 lanes) --------
__global__ void k_gatherA(const int* __restrict__ csr, const int* __restrict__ rowbeg,
                          const int* __restrict__ rowcnt,
                          const float* __restrict__ xtf, const float* __restrict__ xdl,
                          const double* __restrict__ dinv,
                          ull* __restrict__ keys, int N){
  int lane = threadIdx.x & 63;
  int i = (int)((blockIdx.x*(unsigned)blockDim.x + threadIdx.x)>>6);
  if(i>=N) return;
  int beg = rowbeg[i], deg = rowcnt[i];
  int g = lane>>3, t = lane&7;          // 8 groups of 8 lanes; lane covers 8 dims
  double di = dinv[i];
  double a0=0,a1=0,a2=0,a3=0,a4=0,a5=0,a6=0,a7=0;
  int j = g;
  int s = (j<deg) ? csr[beg+j] : 0;
  while(j < deg){
    int snext = (j+8<deg) ? csr[beg+j+8] : 0;       // prefetch next index
    if(s != i){
      double w = di*dinv[s];
      const float4* row = (const float4*)(xtf + (size_t)s*64 + t*8);
      float4 u = row[0], v = row[1];
      a0 -= w*(double)u.x; a1 -= w*(double)u.y; a2 -= w*(double)u.z; a3 -= w*(double)u.w;
      a4 -= w*(double)v.x; a5 -= w*(double)v.y; a6 -= w*(double)v.z; a7 -= w*(double)v.w;
    }
    s = snext; j += 8;
  }
#define XG(v) { v += __shfl_xor(v,8,64); v += __shfl_xor(v,16,64); v += __shfl_xor(v,32,64); }
  XG(a0) XG(a1) XG(a2) XG(a3) XG(a4) XG(a5) XG(a6) XG(a7)
#undef XG
  const float4* xr = (const float4*)(xtf + (size_t)i*64 + t*8);
  const float4* dr = (const float4*)(xdl + (size_t)i*64 + t*8);
  float4 x0 = xr[0], x1 = xr[1], d0 = dr[0], d1 = dr[1];
  double sc =
    fabs(((double)x0.x+(double)d0.x)+a0) + fabs(((double)x0.y+(double)d0.y)+a1) +
    fabs(((double)x0.z+(double)d0.z)+a2) + fabs(((double)x0.w+(double)d0.w)+a3) +
    fabs(((double)x1.x+(double)d1.x)+a4) + fabs(((double)x1.y+(double)d1.y)+a5) +
    fabs(((double)x1.z+(double)d1.z)+a6) + fabs(((double)x1.w+(double)d1.w)+a7);
  sc += __shfl_xor(sc,1,64); sc += __shfl_xor(sc,2,64); sc += __shfl_xor(sc,4,64);
  if(lane==0) keys[i] = (ull)__double_as_longlong(sc);
}

// ---- K5: one 13-bit radix level: LDS hist + global merge + ticketed pick ---
__global__ __launch_bounds__(256) void k_sel13(
    const ull* __restrict__ keys, int N,
    ull* __restrict__ pref, int* __restrict__ rem,
    int lev, int shift, int width,
    int* __restrict__ hist /*SBIN, zeroed*/, int* __restrict__ ticket){
  __shared__ int h[SBIN];
  __shared__ int part[256];
  __shared__ int lastflag, pickedD, pickedR;
  int t = threadIdx.x;
  for(int b=t; b<SBIN; b+=256) h[b] = 0;
  __syncthreads();
  ull p0 = *pref;
  int rem0 = *rem;
  int mask = (1<<width) - 1;
  for(int i = blockIdx.x*256 + t; i<N; i += SELB*256){
    ull kk = keys[i];
    if(lev==0 || (kk >> (shift+width)) == (p0 >> (shift+width)))
      atomicAdd(&h[(int)((kk>>shift)&mask)], 1);
  }
  __syncthreads();
  for(int b=t; b<SBIN; b+=256)
    if(h[b]) __hip_atomic_fetch_add(&hist[b], h[b],
                                    __ATOMIC_RELAXED, __HIP_MEMORY_SCOPE_AGENT);
  __threadfence();
  if(t==0){
    int tk = __hip_atomic_fetch_add(ticket, 1, __ATOMIC_ACQ_REL, __HIP_MEMORY_SCOPE_AGENT);
    lastflag = (tk == SELB-1);
  }
  __syncthreads();
  if(!lastflag) return;
  int base = SBIN-1 - 32*t;               // descending chunked scan
  int pt = 0;
  for(int m=0;m<32;m++)
    pt += __hip_atomic_load(&hist[base-m], __ATOMIC_RELAXED, __HIP_MEMORY_SCOPE_AGENT);
  part[t] = pt;
  __syncthreads();
  for(int off=1; off<256; off<<=1){
    int a = (t>=off) ? part[t-off] : 0; __syncthreads();
    part[t] += a; __syncthreads();
  }
  int cumt = part[t];
  int prev = (t==0) ? 0 : part[t-1];
  if(cumt >= rem0 && prev < rem0){
    int c = 0;
    for(int m=0;m<32;m++){
      int hv = __hip_atomic_load(&hist[base-m], __ATOMIC_RELAXED, __HIP_MEMORY_SCOPE_AGENT);
      c += hv;
      if(prev + c >= rem0){ pickedD = base-m; pickedR = rem0 - (prev + c - hv); break; }
    }
  }
  __syncthreads();
  if(t==0){
    *rem = pickedR;
    *pref = p0 | ((ull)pickedD << shift);
  }
}

// ---- K6: finish: compact 26-bit-prefix candidates, exact rank-select -------
__global__ __launch_bounds__(256) void k_finish(
    const ull* __restrict__ keys, int N,
    ull* __restrict__ pref, const int* __restrict__ rem,
    ull* __restrict__ cand, int* __restrict__ cnt, int* __restrict__ ticket){
  __shared__ ull sc[4096];
  __shared__ int lastflag;
  __shared__ ull winner;
  int t = threadIdx.x;
  ull p0 = *pref;                          // bits 63..38 fixed, low bits 0
  for(int i = blockIdx.x*256 + t; i<N; i += SELB*256){
    ull kk = keys[i];
    if((kk>>38) == (p0>>38)){
      int idx = __hip_atomic_fetch_add(cnt, 1, __ATOMIC_RELAXED, __HIP_MEMORY_SCOPE_AGENT);
      if(idx < CAND_CAP)
        __hip_atomic_store(&cand[idx], kk, __ATOMIC_RELAXED, __HIP_MEMORY_SCOPE_AGENT);
    }
  }
  __threadfence();
  __syncthreads();
  if(t==0){
    int tk = __hip_atomic_fetch_add(ticket, 1, __ATOMIC_ACQ_REL, __HIP_MEMORY_SCOPE_AGENT);
    lastflag = (tk == SELB-1);
  }
  __syncthreads();
  if(!lastflag) return;
  int C = __hip_atomic_load(cnt, __ATOMIC_RELAXED, __HIP_MEMORY_SCOPE_AGENT);
  if(C > 4096) C = 4096;                   // expected C ~ 12
  for(int j=t; j<C; j+=256)
    sc[j] = __hip_atomic_load(&cand[j], __ATOMIC_RELAXED, __HIP_MEMORY_SCOPE_AGENT);
  __syncthreads();
  int r = *rem;                            // rank within prefix group (1-based)
  for(int j=t; j<C; j+=256){
    ull c = sc[j];
    int gt=0, eq=0;
    for(int m=0;m<C;m++){ ull o = sc[m]; gt += (o>c); eq += (o==c); }
    if(gt <= r-1 && r-1 < gt+eq) winner = c;
  }
  __syncthreads();
  if(t==0) *pref = winner;                 // full exact k-th largest key
}

// ---- K7: q[i] = pB + sel*pA (per-source gate contribution) -----------------
__global__ void k_qval(const float2* __restrict__ pab, const ull* __restrict__ keys,
                       const ull* __restrict__ pref, float* __restrict__ q, int N){
  int i = blockIdx.x*blockDim.x + threadIdx.x;
  if(i>=N) return;
  float2 p = pab[i];
  q[i] = p.y + ((keys[i] > *pref) ? p.x : 0.f);
}

// ---- K8: gather C: z = sum q[src]; gg = sel * sigmoid(z+b) -----------------
__global__ void k_gatherC(const int* __restrict__ csr, const int* __restrict__ rowbeg,
                          const int* __restrict__ rowcnt,
                          const float* __restrict__ q,
                          const ull* __restrict__ keys, const ull* __restrict__ pref,
                          const float* __restrict__ lwb,
                          float* __restrict__ gg, int N){
  int lane = threadIdx.x & 63;
  int wid  = (int)((blockIdx.x*(unsigned)blockDim.x + threadIdx.x)>>6);
  int g = lane>>4, t = lane&15;
  int i = wid*4 + g;
  if(i>=N) return;
  int beg = rowbeg[i], end = beg + rowcnt[i];
  float z = 0.f;
  for(int e = beg + t; e < end; e += 16) z += q[csr[e]];
  z = qsumf(z);
  if(t==0){
    float gv = 1.f/(1.f+expf(-(z + lwb[0])));
    gg[i] = (keys[i] > *pref) ? gv : 0.f;
  }
}

// ---- K9: gather D + final chain, 8 rows in flight --------------------------
__global__ void k_gatherD(const int* __restrict__ csr, const int* __restrict__ rowbeg,
                          const int* __restrict__ rowcnt,
                          const float* __restrict__ xtf, const float* __restrict__ gg,
                          float* __restrict__ out, int N){
  int lane = threadIdx.x & 63;
  int i = (int)((blockIdx.x*(unsigned)blockDim.x + threadIdx.x)>>6);
  if(i>=N) return;
  int beg = rowbeg[i], deg = rowcnt[i];
  int g = lane>>3, t = lane&7;          // 8 groups of 8 lanes; lane covers 8 dims
  float c0=0,c1=0,c2=0,c3=0,c4=0,c5=0,c6=0,c7=0;
  int j = g;
  int s = (j<deg) ? csr[beg+j] : 0;
  while(j < deg){
    int snext = (j+8<deg) ? csr[beg+j+8] : 0;
    float gv = gg[s];
    if(gv != 0.f){
      const float4* row = (const float4*)(xtf + (size_t)s*64 + t*8);
      float4 u = row[0], v = row[1];
      c0 = fmaf(gv,u.x,c0); c1 = fmaf(gv,u.y,c1); c2 = fmaf(gv,u.z,c2); c3 = fmaf(gv,u.w,c3);
      c4 = fmaf(gv,v.x,c4); c5 = fmaf(gv,v.y,c5); c6 = fmaf(gv,v.z,c6); c7 = fmaf(gv,v.w,c7);
    }
    s = snext; j += 8;
  }
#define XG(v) { v += __shfl_xor(v,8,64); v += __shfl_xor(v,16,64); v += __shfl_xor(v,32,64); }
  XG(c0) XG(c1) XG(c2) XG(c3) XG(c4) XG(c5) XG(c6) XG(c7)
#undef XG
  const float4* xr = (const float4*)(xtf + (size_t)i*64 + t*8);
  float4 x0 = xr[0], x1 = xr[1];
  float v0 = x0.x + fmaxf(c0,0.f), v1 = x0.y + fmaxf(c1,0.f);
  float v2 = x0.z + fmaxf(c2,0.f), v3 = x0.w + fmaxf(c3,0.f);
  float v4 = x1.x + fmaxf(c4,0.f), v5 = x1.y + fmaxf(c5,0.f);
  float v6 = x1.z + fmaxf(c6,0.f), v7 = x1.w + fmaxf(c7,0.f);
  float n2 = v0*v0+v1*v1+v2*v2+v3*v3+v4*v4+v5*v5+v6*v6+v7*v7;
  n2 += __shfl_xor(n2,1,64); n2 += __shfl_xor(n2,2,64); n2 += __shfl_xor(n2,4,64);
  float n = fmaxf(sqrtf(n2), 1e-15f);
  float f = tanhf(n)/n;                                // expmap0 scale
  float e0=f*v0,e1=f*v1,e2=f*v2,e3=f*v3,e4=f*v4,e5=f*v5,e6=f*v6,e7=f*v7;
  float en = fmaxf(tanhf(n), 1e-15f);                  // |e| = tanh(n)
  if(en > MAXN_F){ float sf = MAXN_F/en;
    e0*=sf;e1*=sf;e2*=sf;e3*=sf;e4*=sf;e5*=sf;e6*=sf;e7*=sf; }
  e0=fmaxf(e0,0.f);e1=fmaxf(e1,0.f);e2=fmaxf(e2,0.f);e3=fmaxf(e3,0.f);
  e4=fmaxf(e4,0.f);e5=fmaxf(e5,0.f);e6=fmaxf(e6,0.f);e7=fmaxf(e7,0.f);
  float m2 = e0*e0+e1*e1+e2*e2+e3*e3+e4*e4+e5*e5+e6*e6+e7*e7;
  m2 += __shfl_xor(m2,1,64); m2 += __shfl_xor(m2,2,64); m2 += __shfl_xor(m2,4,64);
  float nb = fmaxf(sqrtf(m2), 1e-15f);
  float f2 = tanhf(nb)/nb;
  float o0=f2*e0,o1=f2*e1,o2=f2*e2,o3=f2*e3,o4=f2*e4,o5=f2*e5,o6=f2*e6,o7=f2*e7;
  float on = fmaxf(tanhf(nb), 1e-15f);
  if(on > MAXN_F){ float sf = MAXN_F/on;
    o0*=sf;o1*=sf;o2*=sf;o3*=sf;o4*=sf;o5*=sf;o6*=sf;o7*=sf; }
  if(g==0){
    float4* op = (float4*)(out + (size_t)i*64 + t*8);
    op[0] = make_float4(o0,o1,o2,o3);
    op[1] = make_float4(o4,o5,o6,o7);
  }
}

// ---------------------------------------------------------------------------
extern "C" void kernel_launch(void* const* d_in, const int* in_sizes, int n_in,
                              void* d_out, int out_size, void* d_ws, size_t ws_size,
                              hipStream_t stream){
  const float* x    = (const float*)d_in[0];
  const int*   ei   = (const int*)d_in[1];
  const float* W    = (const float*)d_in[2];
  const float* bias = (const float*)d_in[3];
  const float* lww  = (const float*)d_in[4];
  const float* lwb  = (const float*)d_in[5];
  int N = in_sizes[0]/64;
  int E = in_sizes[1]/2;
  int kth = (int)((double)N*0.75);
  int NB = (N+255)>>8;                         // node buckets (256 nodes each)
  if(NB > NBMAX) return;                       // loud failure if N too large
  long long meanPB = (long long)E / (NB > 0 ? NB : 1);
  if(3*meanPB > 2*(long long)BCAP) return;     // require BCAP >= 1.5x mean
  int chunk = (E + BINBLK - 1)/BINBLK;
  size_t binEls = (size_t)NB*BCAP + 4096;      // +slack (OOB insurance)

  char* ws = (char*)d_ws;
  size_t cur = 0;
  auto alloc = [&](size_t bytes){ size_t o = cur; cur = (cur + bytes + 255) & ~(size_t)255; return o; };
  size_t o_hb   = alloc(64*sizeof(double));
  size_t o_hb2  = alloc(8);
  size_t o_rem  = alloc(4);
  size_t o_zero = cur;                         // ---- zeroed region start ----
  size_t o_pref = alloc(8);                    // radix prefix (must start 0)
  size_t o_hist = alloc(2*(size_t)SBIN*4);     // per-level 13-bit hist
  size_t o_tick = alloc(3*4);                  // lev0, lev1, finish tickets
  size_t o_cnt  = alloc(4);                    // candidate count
  size_t zlen   = cur - o_zero;                // ---- zeroed region end ------
  size_t o_cand = alloc((size_t)CAND_CAP*8);
  size_t o_dCur = alloc((size_t)NBMAX*4);
  size_t o_sCur = alloc((size_t)NBMAX*4);
  size_t o_rbeg = alloc((size_t)N*4);
  size_t o_rcnt = alloc((size_t)N*4);
  size_t o_csr  = alloc(binEls*4);
  size_t o_dbin = alloc(binEls*8);
  size_t o_sbin = alloc(binEls*4);
  size_t o_dinv = alloc((size_t)N*8);
  size_t o_keys = alloc((size_t)N*8);
  size_t o_pab  = alloc((size_t)N*8);
  size_t o_q    = alloc((size_t)N*4);
  size_t o_xtf  = alloc((size_t)N*64*4);
  size_t o_xdl  = alloc((size_t)N*64*4);
  size_t o_gg   = alloc((size_t)N*4);
  if(ws_size < cur) return;                    // loud, clean failure

  double* hb     = (double*)(ws+o_hb);
  double* hb2    = (double*)(ws+o_hb2);
  int*    rem    = (int*)(ws+o_rem);
  ull*    pref   = (ull*)(ws+o_pref);
  int*    hist   = (int*)(ws+o_hist);
  int*    tick   = (int*)(ws+o_tick);
  int*    cnt    = (int*)(ws+o_cnt);
  ull*    cand   = (ull*)(ws+o_cand);
  int*    dstCur = (int*)(ws+o_dCur);
  int*    srcCur = (int*)(ws+o_sCur);
  int*    rowbeg = (int*)(ws+o_rbeg);
  int*    rowcnt = (int*)(ws+o_rcnt);
  int*    csr    = (int*)(ws+o_csr);
  ull*    dstbin = (ull*)(ws+o_dbin);
  int*    srcbin = (int*)(ws+o_sbin);
  double* dinv   = (double*)(ws+o_dinv);
  ull*    keys   = (ull*)(ws+o_keys);
  float2* pab    = (float2*)(ws+o_pab);
  float*  q      = (float*)(ws+o_q);
  float*  xtf    = (float*)(ws+o_xtf);
  float*  xdl    = (float*)(ws+o_xdl);
  float*  gg     = (float*)(ws+o_gg);

  hipMemsetAsync(ws+o_zero, 0, zlen, stream);

  int nodeBlocks = (N+3)/4;                    // 1 wave per node
  int pBlocks    = (N+15)/16;                  // 4 nodes per wave

  k_init     <<<1, 256, 0, stream>>>(bias, hb, hb2, rem, kth, dstCur, srcCur, NB);
  k_binPlace <<<BINBLK, 256, 0, stream>>>(ei, E, NB, chunk, dstCur, srcCur, dstbin, srcbin);
  k_bucketAB <<<NB, 256, 0, stream>>>(dstbin, dstCur, rowbeg, rowcnt, csr,
                                      srcbin, srcCur, dinv, N);
  k_gemmprep <<<(N+NPB-1)/NPB, GPT, 0, stream>>>(x, W, hb, hb2, lww, xtf, xdl, pab, N);
  k_gatherA  <<<nodeBlocks, 256, 0, stream>>>(csr, rowbeg, rowcnt, xtf, xdl, dinv, keys, N);
  k_sel13    <<<SELB, 256, 0, stream>>>(keys, N, pref, rem, 0, 51, 13, hist, tick+0);
  k_sel13    <<<SELB, 256, 0, stream>>>(keys, N, pref, rem, 1, 38, 13, hist+SBIN, tick+1);
  k_finish   <<<SELB, 256, 0, stream>>>(keys, N, pref, rem, cand, cnt, tick+2);
  k_qval     <<<(N+255)/256, 256, 0, stream>>>(pab, keys, pref, q, N);
  k_gatherC  <<<pBlocks, 256, 0, stream>>>(csr, rowbeg, rowcnt, q, keys, pref, lwb, gg, N);
  k_gatherD  <<<nodeBlocks, 256, 0, stream>>>(csr, rowbeg, rowcnt, xtf, gg, (float*)d_out, N);
}

// Round 19
// 338.234 us; speedup vs baseline: 1.0777x; 1.0007x over previous
//
#include <hip/hip_runtime.h>
#include <hip/hip_fp16.h>
#include <math.h>

// ---------------------------------------------------------------------------
// HyperbolicGraphConvolution (HGCN HypLinear + NodeSelect + HypAct), c=1.
// Round 19: f16 gathered rows for gatherD. xth = (half)x_tan written in
// gemmprep (+13MB write); gatherD gathers 128B/edge instead of 256B. Score/
// select path untouched (gatherA still f32 xtf -> keys bit-identical).
// Output error budget: +<=4e-4 worst case vs 3.24e-3 threshold.
// Rest identical to R18.
// ---------------------------------------------------------------------------

#define MAXN_D 0.996      // (1 - 4e-3)/sqrt(c), c=1
#define MAXN_F 0.996f
#define NPB 64            // nodes per block in k_gemmprep (8 per wave, 8 waves)
#define GPT 512           // gemmprep threads per block
#define NBMAX 512         // max buckets (N <= 131072)
#define BCAP 6144         // static bucket capacity (mean 3072, sigma 55)
#define BINBLK 256        // blocks in bin kernels
#define SELB 128          // blocks per select level
#define SBIN 8192         // 13-bit radix bins
#define CAND_CAP 16384    // finish-stage candidate cap (expect ~12)

typedef unsigned long long ull;

__device__ __forceinline__ double wsumd(double v){
#pragma unroll
  for(int o=32;o;o>>=1) v += __shfl_xor(v,o,64);
  return v;
}
__device__ __forceinline__ float wsumf(float v){
#pragma unroll
  for(int o=32;o;o>>=1) v += __shfl_xor(v,o,64);
  return v;
}
__device__ __forceinline__ float qsumf(float v){
#pragma unroll
  for(int o=1;o<16;o<<=1) v += __shfl_xor(v,o,64);
  return v;
}

// ---- K0: hyp_bias (double) + |hb|^2 + rem + static bucket cursors ----------
__global__ __launch_bounds__(256) void k_init(
    const float* __restrict__ bias, double* __restrict__ hb,
    double* __restrict__ hb2, int* __restrict__ rem, int kth,
    int* __restrict__ dstCur, int* __restrict__ srcCur, int NB){
  if(threadIdx.x < 64){
    int lane = threadIdx.x;
    double b = (double)bias[lane];
    double n = fmax(sqrt(wsumd(b*b)), 1e-15);
    double e = tanh(n)*b/n;                       // expmap0, sc=1
    double en = fmax(sqrt(wsumd(e*e)), 1e-15);
    if(en > MAXN_D) e *= MAXN_D/en;               // proj
    hb[lane] = e;
    double s2 = wsumd(e*e);
    if(lane==0) *hb2 = s2;
  }
  if(threadIdx.x == 0) *rem = kth;
  for(int b=threadIdx.x; b<NB; b+=256){
    dstCur[b] = b*BCAP;
    srcCur[b] = b*BCAP;
  }
}

// ---- K1: bin place into static-cap regions (line-dense binned writes) ------
__global__ __launch_bounds__(256) void k_binPlace(const int* __restrict__ ei, int E,
    int NB, int chunk, int* __restrict__ dstCur, int* __restrict__ srcCur,
    ull* __restrict__ dstbin, int* __restrict__ srcbin){
  __shared__ int dh[NBMAX], sh_[NBMAX];
  __shared__ int db[NBMAX], sb[NBMAX];
  for(int t=threadIdx.x; t<NB; t+=256){ dh[t]=0; sh_[t]=0; }
  __syncthreads();
  int start = blockIdx.x*chunk, end = min(E, start+chunk);
  for(int e=start+(int)threadIdx.x; e<end; e+=256){
    int s = ei[e], d = ei[(size_t)E+e];
    atomicAdd(&dh[d>>8],1);
    if(s!=d) atomicAdd(&sh_[s>>8],1);
  }
  __syncthreads();
  for(int t=threadIdx.x; t<NB; t+=256){
    db[t] = dh[t]  ? atomicAdd(&dstCur[t], dh[t])  : 0;
    sb[t] = sh_[t] ? atomicAdd(&srcCur[t], sh_[t]) : 0;
  }
  __syncthreads();
  for(int t=threadIdx.x; t<NB; t+=256){ dh[t]=db[t]; sh_[t]=sb[t]; }
  __syncthreads();
  for(int e=start+(int)threadIdx.x; e<end; e+=256){
    int s = ei[e], d = ei[(size_t)E+e];
    int p = atomicAdd(&dh[d>>8],1);
    dstbin[p] = ((ull)(unsigned)d<<32) | (unsigned)s;
    if(s!=d){ int p2 = atomicAdd(&sh_[s>>8],1); srcbin[p2] = s; }
  }
}

// ---- K2: per bucket: dst->rowbeg/rowcnt/csr, then src->dinv ----------------
__global__ __launch_bounds__(256) void k_bucketAB(
    const ull* __restrict__ dstbin, const int* __restrict__ dstCur,
    int* __restrict__ rowbeg, int* __restrict__ rowcnt, int* __restrict__ csr,
    const int* __restrict__ srcbin, const int* __restrict__ srcCur,
    double* __restrict__ dinv, int N){
  int b = blockIdx.x;
  int node0 = b<<8;
  int nodes = min(256, N-node0);
  __shared__ int c[256], ex[256];
  int t = threadIdx.x;
  {
    int base = b*BCAP, cnt = dstCur[b]-base;
    c[t]=0; __syncthreads();
    for(int e=base+t; e<base+cnt; e+=256){
      int d = (int)(dstbin[e]>>32);
      atomicAdd(&c[d-node0],1);
    }
    __syncthreads();
    int v = c[t]; ex[t]=v; __syncthreads();
    for(int off=1; off<256; off<<=1){
      int a = (t>=off) ? ex[t-off] : 0; __syncthreads();
      ex[t] += a; __syncthreads();
    }
    int mybase = base + ex[t] - v;
    if(t<nodes){ rowbeg[node0+t] = mybase; rowcnt[node0+t] = v; }
    c[t] = mybase;
    __syncthreads();
    for(int e=base+t; e<base+cnt; e+=256){
      ull pr = dstbin[e];
      int d = (int)(pr>>32);
      int p = atomicAdd(&c[d-node0],1);
      csr[p] = (int)(pr & 0xffffffffu);
    }
  }
  __syncthreads();
  {
    int base = b*BCAP, cnt = srcCur[b]-base;
    c[t]=0; __syncthreads();
    for(int e=base+t; e<base+cnt; e+=256)
      atomicAdd(&c[srcbin[e]-node0],1);
    __syncthreads();
    if(t<nodes){ int d = c[t]; dinv[node0+t] = (d>0) ? 1.0/sqrt((double)d) : 0.0; }
  }
}

// ---- K3: fused gemm + reductions + block-dedup'd chain + writes ------------
__global__ __launch_bounds__(GPT) void k_gemmprep(
    const float* __restrict__ x, const float* __restrict__ W,
    const double* __restrict__ hb, const double* __restrict__ hb2p,
    const float* __restrict__ lww,
    float* __restrict__ xtf, float* __restrict__ xdl, __half* __restrict__ xth,
    float2* __restrict__ pab, int N){
  __shared__ float wf[4096];        // [k4][j][m]: flat k4*256 + j*4 + m (16KB)
  __shared__ float xf[NPB*64];      // [n][k] f32 (16KB)
  __shared__ double r123[NPB][3];   // per-node reduction triple (1.5KB)
  __shared__ double abuf[NPB][2];   // per-node alpha,beta (1KB)
  int tid = threadIdx.x;
  for(int a=tid; a<4096; a+=GPT){   // linear LDS writes; W gathered from L1
    int j = (a>>2)&63;
    int k = ((a>>8)<<2) | (a&3);
    wf[a] = W[j*64 + k];
  }
  int i0 = blockIdx.x*NPB;
  for(int idx=tid; idx<NPB*64; idx+=GPT){
    int node = i0 + (idx>>6);
    xf[idx] = (node<N) ? x[(size_t)node*64 + (idx&63)] : 0.f;
  }
  __syncthreads();
  int lane = tid & 63;
  int nb = (tid>>6)*8;              // this wave's first node-in-block (8/wave)
  double acc0=0.0, acc1=0.0, acc2=0.0, acc3=0.0;
  double acc4=0.0, acc5=0.0, acc6=0.0, acc7=0.0;
  const float4* wq = (const float4*)wf;   // wq[k4*64 + lane]
  const float4* xq = (const float4*)xf;   // xq[node_local*16 + k4]
#pragma unroll 2
  for(int k4=0; k4<16; ++k4){
    float4 w4 = wq[k4*64 + lane];
    double w0=(double)w4.x, w1=(double)w4.y, w2d=(double)w4.z, w3=(double)w4.w;
#define MAC(n, accn) { float4 v = xq[(nb+(n))*16 + k4];                       \
    accn = fma(w0,(double)v.x,accn); accn = fma(w1,(double)v.y,accn);         \
    accn = fma(w2d,(double)v.z,accn); accn = fma(w3,(double)v.w,accn); }
    MAC(0,acc0) MAC(1,acc1) MAC(2,acc2) MAC(3,acc3)
    MAC(4,acc4) MAC(5,acc5) MAC(6,acc6) MAC(7,acc7)
#undef MAC
  }
  double hbl = hb[lane];
  // ---- reductions for 8 nodes -> r123 LDS ---------------------------------
#define RED4(A0,A1,A2,A3, OFF) {                                              \
    double xd0 = (double)xf[(nb+(OFF)+0)*64+lane];                            \
    double xd1 = (double)xf[(nb+(OFF)+1)*64+lane];                            \
    double xd2 = (double)xf[(nb+(OFF)+2)*64+lane];                            \
    double xd3 = (double)xf[(nb+(OFF)+3)*64+lane];                            \
    double s1_0 = wsumd(xd0*xd0), s2_0 = wsumd((A0)*(A0)), s3_0 = wsumd((A0)*hbl); \
    double s1_1 = wsumd(xd1*xd1), s2_1 = wsumd((A1)*(A1)), s3_1 = wsumd((A1)*hbl); \
    double s1_2 = wsumd(xd2*xd2), s2_2 = wsumd((A2)*(A2)), s3_2 = wsumd((A2)*hbl); \
    double s1_3 = wsumd(xd3*xd3), s2_3 = wsumd((A3)*(A3)), s3_3 = wsumd((A3)*hbl); \
    if(lane==0){                                                              \
      r123[nb+(OFF)+0][0]=s1_0; r123[nb+(OFF)+0][1]=s2_0; r123[nb+(OFF)+0][2]=s3_0; \
      r123[nb+(OFF)+1][0]=s1_1; r123[nb+(OFF)+1][1]=s2_1; r123[nb+(OFF)+1][2]=s3_1; \
      r123[nb+(OFF)+2][0]=s1_2; r123[nb+(OFF)+2][1]=s2_2; r123[nb+(OFF)+2][2]=s3_2; \
      r123[nb+(OFF)+3][0]=s1_3; r123[nb+(OFF)+3][1]=s2_3; r123[nb+(OFF)+3][2]=s3_3; \
    } }
  RED4(acc0,acc1,acc2,acc3, 0)
  RED4(acc4,acc5,acc6,acc7, 4)
#undef RED4
  __syncthreads();
  // ---- chain: wave 0 only, lane = node-in-block ---------------------------
  if(tid < 64){
    double x2s = r123[tid][0], m2 = r123[tid][1], mh = r123[tid][2];
    double y2 = *hb2p;
    double xn  = fmax(sqrt(x2s), 1e-15);
    double mxn = fmax(sqrt(m2), 1e-15);
    double xc  = fmin(fmax(xn, -1.0+1e-7), 1.0-1e-7);
    double at  = 0.5*(log1p(xc)-log1p(-xc));        // artanh(|x|)
    double f1  = tanh(mxn/xn*at)/mxn;               // h = f1*mx
    if(m2 == 0.0) f1 = 0.0;
    double h2 = f1*f1*m2;
    double hn = fmax(sqrt(h2), 1e-15);
    if(hn > MAXN_D){ double s = MAXN_D/hn; f1 *= s; h2 = f1*f1*m2; }   // proj(h)
    double xy = f1*mh;
    double den = fmax(1.0 + 2.0*xy + h2*y2, 1e-15);
    double a = (1.0 + 2.0*xy + y2)/den;
    double bb = (1.0 - h2)/den;
    double p2 = a*a*h2 + 2.0*a*bb*xy + bb*bb*y2;
    double pn = fmax(sqrt(p2), 1e-15);
    if(pn > MAXN_D){ double s = MAXN_D/pn; a*=s; bb*=s; pn = fmax(pn*s, 1e-15); }
    double nc  = fmin(fmax(pn, -1.0+1e-7), 1.0-1e-7);
    double at2 = 0.5*(log1p(nc)-log1p(-nc));        // artanh(|p|)
    double sc  = at2/pn;                            // logmap0 scale
    abuf[tid][0] = sc*a*f1;
    abuf[tid][1] = sc*bb;
  }
  __syncthreads();
  // ---- emit: xtf + f32 delta + f16 mirror ---------------------------------
  float wAl = lww[lane], wBl = lww[64+lane];
#define EMIT(n, accn) { int nd=i0+nb+(n); if(nd<N){                           \
    double al = abuf[nb+(n)][0], be = abuf[nb+(n)][1];                        \
    double v = al*(accn) + be*hbl;                                            \
    float vf = (float)v;                                                      \
    float df = (float)(v - (double)vf);                                       \
    xtf[(size_t)nd*64+lane] = vf;                                             \
    xdl[(size_t)nd*64+lane] = df;                                             \
    xth[(size_t)nd*64+lane] = __float2half(vf);                               \
    float pA = wsumf(vf*wAl);                                                 \
    float pB = wsumf(vf*wBl);                                                 \
    if(lane==0) pab[nd] = make_float2(pA,pB); } }
  EMIT(0,acc0) EMIT(1,acc1) EMIT(2,acc2) EMIT(3,acc3)
  EMIT(4,acc4) EMIT(5,acc5) EMIT(6,acc6) EMIT(7,acc7)
#undef EMIT
}

// ---- K4: gather A: score key, 8 rows in flight (8 groups x 8 lanes) --------
__global__ void k_gatherA(const int* __restrict__ csr, const int* __restrict__ rowbeg,
                          const int* __restrict__ rowcnt,
                          const float* __restrict__ xtf, const float* __restrict__ xdl,
                          const double* __restrict__ dinv,
                          ull* __restrict__ keys, int N){
  int lane = threadIdx.x & 63;
  int i = (int)((blockIdx.x*(unsigned)blockDim.x + threadIdx.x)>>6);
  if(i>=N) return;
  int beg = rowbeg[i], deg = rowcnt[i];
  int g = lane>>3, t = lane&7;          // 8 groups of 8 lanes; lane covers 8 dims
  double di = dinv[i];
  double a0=0,a1=0,a2=0,a3=0,a4=0,a5=0,a6=0,a7=0;
  int j = g;
  int s = (j<deg) ? csr[beg+j] : 0;
  while(j < deg){
    int snext = (j+8<deg) ? csr[beg+j+8] : 0;       // prefetch next index
    if(s != i){
      double w = di*dinv[s];
      const float4* row = (const float4*)(xtf + (size_t)s*64 + t*8);
      float4 u = row[0], v = row[1];
      a0 -= w*(double)u.x; a1 -= w*(double)u.y; a2 -= w*(double)u.z; a3 -= w*(double)u.w;
      a4 -= w*(double)v.x; a5 -= w*(double)v.y; a6 -= w*(double)v.z; a7 -= w*(double)v.w;
    }
    s = snext; j += 8;
  }
#define XG(v) { v += __shfl_xor(v,8,64); v += __shfl_xor(v,16,64); v += __shfl_xor(v,32,64); }
  XG(a0) XG(a1) XG(a2) XG(a3) XG(a4) XG(a5) XG(a6) XG(a7)
#undef XG
  const float4* xr = (const float4*)(xtf + (size_t)i*64 + t*8);
  const float4* dr = (const float4*)(xdl + (size_t)i*64 + t*8);
  float4 x0 = xr[0], x1 = xr[1], d0 = dr[0], d1 = dr[1];
  double sc =
    fabs(((double)x0.x+(double)d0.x)+a0) + fabs(((double)x0.y+(double)d0.y)+a1) +
    fabs(((double)x0.z+(double)d0.z)+a2) + fabs(((double)x0.w+(double)d0.w)+a3) +
    fabs(((double)x1.x+(double)d1.x)+a4) + fabs(((double)x1.y+(double)d1.y)+a5) +
    fabs(((double)x1.z+(double)d1.z)+a6) + fabs(((double)x1.w+(double)d1.w)+a7);
  sc += __shfl_xor(sc,1,64); sc += __shfl_xor(sc,2,64); sc += __shfl_xor(sc,4,64);
  if(lane==0) keys[i] = (ull)__double_as_longlong(sc);
}

// ---- K5: one 13-bit radix level: LDS hist + global merge + ticketed pick ---
__global__ __launch_bounds__(256) void k_sel13(
    const ull* __restrict__ keys, int N,
    ull* __restrict__ pref, int* __restrict__ rem,
    int lev, int shift, int width,
    int* __restrict__ hist /*SBIN, zeroed*/, int* __restrict__ ticket){
  __shared__ int h[SBIN];
  __shared__ int part[256];
  __shared__ int lastflag, pickedD, pickedR;
  int t = threadIdx.x;
  for(int b=t; b<SBIN; b+=256) h[b] = 0;
  __syncthreads();
  ull p0 = *pref;
  int rem0 = *rem;
  int mask = (1<<width) - 1;
  for(int i = blockIdx.x*256 + t; i<N; i += SELB*256){
    ull kk = keys[i];
    if(lev==0 || (kk >> (shift+width)) == (p0 >> (shift+width)))
      atomicAdd(&h[(int)((kk>>shift)&mask)], 1);
  }
  __syncthreads();
  for(int b=t; b<SBIN; b+=256)
    if(h[b]) __hip_atomic_fetch_add(&hist[b], h[b],
                                    __ATOMIC_RELAXED, __HIP_MEMORY_SCOPE_AGENT);
  __threadfence();
  if(t==0){
    int tk = __hip_atomic_fetch_add(ticket, 1, __ATOMIC_ACQ_REL, __HIP_MEMORY_SCOPE_AGENT);
    lastflag = (tk == SELB-1);
  }
  __syncthreads();
  if(!lastflag) return;
  int base = SBIN-1 - 32*t;               // descending chunked scan
  int pt = 0;
  for(int m=0;m<32;m++)
    pt += __hip_atomic_load(&hist[base-m], __ATOMIC_RELAXED, __HIP_MEMORY_SCOPE_AGENT);
  part[t] = pt;
  __syncthreads();
  for(int off=1; off<256; off<<=1){
    int a = (t>=off) ? part[t-off] : 0; __syncthreads();
    part[t] += a; __syncthreads();
  }
  int cumt = part[t];
  int prev = (t==0) ? 0 : part[t-1];
  if(cumt >= rem0 && prev < rem0){
    int c = 0;
    for(int m=0;m<32;m++){
      int hv = __hip_atomic_load(&hist[base-m], __ATOMIC_RELAXED, __HIP_MEMORY_SCOPE_AGENT);
      c += hv;
      if(prev + c >= rem0){ pickedD = base-m; pickedR = rem0 - (prev + c - hv); break; }
    }
  }
  __syncthreads();
  if(t==0){
    *rem = pickedR;
    *pref = p0 | ((ull)pickedD << shift);
  }
}

// ---- K6: finish: compact 26-bit-prefix candidates, exact rank-select -------
__global__ __launch_bounds__(256) void k_finish(
    const ull* __restrict__ keys, int N,
    ull* __restrict__ pref, const int* __restrict__ rem,
    ull* __restrict__ cand, int* __restrict__ cnt, int* __restrict__ ticket){
  __shared__ ull sc[4096];
  __shared__ int lastflag;
  __shared__ ull winner;
  int t = threadIdx.x;
  ull p0 = *pref;                          // bits 63..38 fixed, low bits 0
  for(int i = blockIdx.x*256 + t; i<N; i += SELB*256){
    ull kk = keys[i];
    if((kk>>38) == (p0>>38)){
      int idx = __hip_atomic_fetch_add(cnt, 1, __ATOMIC_RELAXED, __HIP_MEMORY_SCOPE_AGENT);
      if(idx < CAND_CAP)
        __hip_atomic_store(&cand[idx], kk, __ATOMIC_RELAXED, __HIP_MEMORY_SCOPE_AGENT);
    }
  }
  __threadfence();
  __syncthreads();
  if(t==0){
    int tk = __hip_atomic_fetch_add(ticket, 1, __ATOMIC_ACQ_REL, __HIP_MEMORY_SCOPE_AGENT);
    lastflag = (tk == SELB-1);
  }
  __syncthreads();
  if(!lastflag) return;
  int C = __hip_atomic_load(cnt, __ATOMIC_RELAXED, __HIP_MEMORY_SCOPE_AGENT);
  if(C > 4096) C = 4096;                   // expected C ~ 12
  for(int j=t; j<C; j+=256)
    sc[j] = __hip_atomic_load(&cand[j], __ATOMIC_RELAXED, __HIP_MEMORY_SCOPE_AGENT);
  __syncthreads();
  int r = *rem;                            // rank within prefix group (1-based)
  for(int j=t; j<C; j+=256){
    ull c = sc[j];
    int gt=0, eq=0;
    for(int m=0;m<C;m++){ ull o = sc[m]; gt += (o>c); eq += (o==c); }
    if(gt <= r-1 && r-1 < gt+eq) winner = c;
  }
  __syncthreads();
  if(t==0) *pref = winner;                 // full exact k-th largest key
}

// ---- K7: q[i] = pB + sel*pA (per-source gate contribution) -----------------
__global__ void k_qval(const float2* __restrict__ pab, const ull* __restrict__ keys,
                       const ull* __restrict__ pref, float* __restrict__ q, int N){
  int i = blockIdx.x*blockDim.x + threadIdx.x;
  if(i>=N) return;
  float2 p = pab[i];
  q[i] = p.y + ((keys[i] > *pref) ? p.x : 0.f);
}

// ---- K8: gather C: z = sum q[src]; gg = sel * sigmoid(z+b) -----------------
__global__ void k_gatherC(const int* __restrict__ csr, const int* __restrict__ rowbeg,
                          const int* __restrict__ rowcnt,
                          const float* __restrict__ q,
                          const ull* __restrict__ keys, const ull* __restrict__ pref,
                          const float* __restrict__ lwb,
                          float* __restrict__ gg, int N){
  int lane = threadIdx.x & 63;
  int wid  = (int)((blockIdx.x*(unsigned)blockDim.x + threadIdx.x)>>6);
  int g = lane>>4, t = lane&15;
  int i = wid*4 + g;
  if(i>=N) return;
  int beg = rowbeg[i], end = beg + rowcnt[i];
  float z = 0.f;
  for(int e = beg + t; e < end; e += 16) z += q[csr[e]];
  z = qsumf(z);
  if(t==0){
    float gv = 1.f/(1.f+expf(-(z + lwb[0])));
    gg[i] = (keys[i] > *pref) ? gv : 0.f;
  }
}

// ---- K9: gather D + final chain, 8 f16 rows in flight ----------------------
__global__ void k_gatherD(const int* __restrict__ csr, const int* __restrict__ rowbeg,
                          const int* __restrict__ rowcnt,
                          const float* __restrict__ xtf, const __half* __restrict__ xth,
                          const float* __restrict__ gg,
                          float* __restrict__ out, int N){
  int lane = threadIdx.x & 63;
  int i = (int)((blockIdx.x*(unsigned)blockDim.x + threadIdx.x)>>6);
  if(i>=N) return;
  int beg = rowbeg[i], deg = rowcnt[i];
  int g = lane>>3, t = lane&7;          // 8 groups of 8 lanes; lane covers 8 dims
  float c0=0,c1=0,c2=0,c3=0,c4=0,c5=0,c6=0,c7=0;
  int j = g;
  int s = (j<deg) ? csr[beg+j] : 0;
  while(j < deg){
    int snext = (j+8<deg) ? csr[beg+j+8] : 0;
    float gv = gg[s];
    if(gv != 0.f){
      float4 raw = *(const float4*)(xth + (size_t)s*64 + t*8);   // 8 halves, 16B
      const __half2* hp = (const __half2*)&raw;
      float2 p0 = __half22float2(hp[0]);
      float2 p1 = __half22float2(hp[1]);
      float2 p2 = __half22float2(hp[2]);
      float2 p3 = __half22float2(hp[3]);
      c0 = fmaf(gv,p0.x,c0); c1 = fmaf(gv,p0.y,c1); c2 = fmaf(gv,p1.x,c2); c3 = fmaf(gv,p1.y,c3);
      c4 = fmaf(gv,p2.x,c4); c5 = fmaf(gv,p2.y,c5); c6 = fmaf(gv,p3.x,c6); c7 = fmaf(gv,p3.y,c7);
    }
    s = snext; j += 8;
  }
#define XG(v) { v += __shfl_xor(v,8,64); v += __shfl_xor(v,16,64); v += __shfl_xor(v,32,64); }
  XG(c0) XG(c1) XG(c2) XG(c3) XG(c4) XG(c5) XG(c6) XG(c7)
#undef XG
  const float4* xr = (const float4*)(xtf + (size_t)i*64 + t*8);
  float4 x0 = xr[0], x1 = xr[1];
  float v0 = x0.x + fmaxf(c0,0.f), v1 = x0.y + fmaxf(c1,0.f);
  float v2 = x0.z + fmaxf(c2,0.f), v3 = x0.w + fmaxf(c3,0.f);
  float v4 = x1.x + fmaxf(c4,0.f), v5 = x1.y + fmaxf(c5,0.f);
  float v6 = x1.z + fmaxf(c6,0.f), v7 = x1.w + fmaxf(c7,0.f);
  float n2 = v0*v0+v1*v1+v2*v2+v3*v3+v4*v4+v5*v5+v6*v6+v7*v7;
  n2 += __shfl_xor(n2,1,64); n2 += __shfl_xor(n2,2,64); n2 += __shfl_xor(n2,4,64);
  float n = fmaxf(sqrtf(n2), 1e-15f);
  float f = tanhf(n)/n;                                // expmap0 scale
  float e0=f*v0,e1=f*v1,e2=f*v2,e3=f*v3,e4=f*v4,e5=f*v5,e6=f*v6,e7=f*v7;
  float en = fmaxf(tanhf(n), 1e-15f);                  // |e| = tanh(n)
  if(en > MAXN_F){ float sf = MAXN_F/en;
    e0*=sf;e1*=sf;e2*=sf;e3*=sf;e4*=sf;e5*=sf;e6*=sf;e7*=sf; }
  e0=fmaxf(e0,0.f);e1=fmaxf(e1,0.f);e2=fmaxf(e2,0.f);e3=fmaxf(e3,0.f);
  e4=fmaxf(e4,0.f);e5=fmaxf(e5,0.f);e6=fmaxf(e6,0.f);e7=fmaxf(e7,0.f);
  float m2 = e0*e0+e1*e1+e2*e2+e3*e3+e4*e4+e5*e5+e6*e6+e7*e7;
  m2 += __shfl_xor(m2,1,64); m2 += __shfl_xor(m2,2,64); m2 += __shfl_xor(m2,4,64);
  float nb = fmaxf(sqrtf(m2), 1e-15f);
  float f2 = tanhf(nb)/nb;
  float o0=f2*e0,o1=f2*e1,o2=f2*e2,o3=f2*e3,o4=f2*e4,o5=f2*e5,o6=f2*e6,o7=f2*e7;
  float on = fmaxf(tanhf(nb), 1e-15f);
  if(on > MAXN_F){ float sf = MAXN_F/on;
    o0*=sf;o1*=sf;o2*=sf;o3*=sf;o4*=sf;o5*=sf;o6*=sf;o7*=sf; }
  if(g==0){
    float4* op = (float4*)(out + (size_t)i*64 + t*8);
    op[0] = make_float4(o0,o1,o2,o3);
    op[1] = make_float4(o4,o5,o6,o7);
  }
}

// ---------------------------------------------------------------------------
extern "C" void kernel_launch(void* const* d_in, const int* in_sizes, int n_in,
                              void* d_out, int out_size, void* d_ws, size_t ws_size,
                              hipStream_t stream){
  const float* x    = (const float*)d_in[0];
  const int*   ei   = (const int*)d_in[1];
  const float* W    = (const float*)d_in[2];
  const float* bias = (const float*)d_in[3];
  const float* lww  = (const float*)d_in[4];
  const float* lwb  = (const float*)d_in[5];
  int N = in_sizes[0]/64;
  int E = in_sizes[1]/2;
  int kth = (int)((double)N*0.75);
  int NB = (N+255)>>8;                         // node buckets (256 nodes each)
  if(NB > NBMAX) return;                       // loud failure if N too large
  long long meanPB = (long long)E / (NB > 0 ? NB : 1);
  if(3*meanPB > 2*(long long)BCAP) return;     // require BCAP >= 1.5x mean
  int chunk = (E + BINBLK - 1)/BINBLK;
  size_t binEls = (size_t)NB*BCAP + 4096;      // +slack (OOB insurance)

  char* ws = (char*)d_ws;
  size_t cur = 0;
  auto alloc = [&](size_t bytes){ size_t o = cur; cur = (cur + bytes + 255) & ~(size_t)255; return o; };
  size_t o_hb   = alloc(64*sizeof(double));
  size_t o_hb2  = alloc(8);
  size_t o_rem  = alloc(4);
  size_t o_zero = cur;                         // ---- zeroed region start ----
  size_t o_pref = alloc(8);                    // radix prefix (must start 0)
  size_t o_hist = alloc(2*(size_t)SBIN*4);     // per-level 13-bit hist
  size_t o_tick = alloc(3*4);                  // lev0, lev1, finish tickets
  size_t o_cnt  = alloc(4);                    // candidate count
  size_t zlen   = cur - o_zero;                // ---- zeroed region end ------
  size_t o_cand = alloc((size_t)CAND_CAP*8);
  size_t o_dCur = alloc((size_t)NBMAX*4);
  size_t o_sCur = alloc((size_t)NBMAX*4);
  size_t o_rbeg = alloc((size_t)N*4);
  size_t o_rcnt = alloc((size_t)N*4);
  size_t o_csr  = alloc(binEls*4);
  size_t o_dbin = alloc(binEls*8);
  size_t o_sbin = alloc(binEls*4);
  size_t o_dinv = alloc((size_t)N*8);
  size_t o_keys = alloc((size_t)N*8);
  size_t o_pab  = alloc((size_t)N*8);
  size_t o_q    = alloc((size_t)N*4);
  size_t o_xtf  = alloc((size_t)N*64*4);
  size_t o_xdl  = alloc((size_t)N*64*4);
  size_t o_xth  = alloc((size_t)N*64*2);
  size_t o_gg   = alloc((size_t)N*4);
  if(ws_size < cur) return;                    // loud, clean failure

  double* hb     = (double*)(ws+o_hb);
  double* hb2    = (double*)(ws+o_hb2);
  int*    rem    = (int*)(ws+o_rem);
  ull*    pref   = (ull*)(ws+o_pref);
  int*    hist   = (int*)(ws+o_hist);
  int*    tick   = (int*)(ws+o_tick);
  int*    cnt    = (int*)(ws+o_cnt);
  ull*    cand   = (ull*)(ws+o_cand);
  int*    dstCur = (int*)(ws+o_dCur);
  int*    srcCur = (int*)(ws+o_sCur);
  int*    rowbeg = (int*)(ws+o_rbeg);
  int*    rowcnt = (int*)(ws+o_rcnt);
  int*    csr    = (int*)(ws+o_csr);
  ull*    dstbin = (ull*)(ws+o_dbin);
  int*    srcbin = (int*)(ws+o_sbin);
  double* dinv   = (double*)(ws+o_dinv);
  ull*    keys   = (ull*)(ws+o_keys);
  float2* pab    = (float2*)(ws+o_pab);
  float*  q      = (float*)(ws+o_q);
  float*  xtf    = (float*)(ws+o_xtf);
  float*  xdl    = (float*)(ws+o_xdl);
  __half* xth    = (__half*)(ws+o_xth);
  float*  gg     = (float*)(ws+o_gg);

  hipMemsetAsync(ws+o_zero, 0, zlen, stream);

  int nodeBlocks = (N+3)/4;                    // 1 wave per node
  int pBlocks    = (N+15)/16;                  // 4 nodes per wave

  k_init     <<<1, 256, 0, stream>>>(bias, hb, hb2, rem, kth, dstCur, srcCur, NB);
  k_binPlace <<<BINBLK, 256, 0, stream>>>(ei, E, NB, chunk, dstCur, srcCur, dstbin, srcbin);
  k_bucketAB <<<NB, 256, 0, stream>>>(dstbin, dstCur, rowbeg, rowcnt, csr,
                                      srcbin, srcCur, dinv, N);
  k_gemmprep <<<(N+NPB-1)/NPB, GPT, 0, stream>>>(x, W, hb, hb2, lww, xtf, xdl, xth, pab, N);
  k_gatherA  <<<nodeBlocks, 256, 0, stream>>>(csr, rowbeg, rowcnt, xtf, xdl, dinv, keys, N);
  k_sel13    <<<SELB, 256, 0, stream>>>(keys, N, pref, rem, 0, 51, 13, hist, tick+0);
  k_sel13    <<<SELB, 256, 0, stream>>>(keys, N, pref, rem, 1, 38, 13, hist+SBIN, tick+1);
  k_finish   <<<SELB, 256, 0, stream>>>(keys, N, pref, rem, cand, cnt, tick+2);
  k_qval     <<<(N+255)/256, 256, 0, stream>>>(pab, keys, pref, q, N);
  k_gatherC  <<<pBlocks, 256, 0, stream>>>(csr, rowbeg, rowcnt, q, keys, pref, lwb, gg, N);
  k_gatherD  <<<nodeBlocks, 256, 0, stream>>>(csr, rowbeg, rowcnt, xtf, xth, gg, (float*)d_out, N);
}

// Round 20
// 317.905 us; speedup vs baseline: 1.1466x; 1.0639x over previous
//
#include <hip/hip_runtime.h>
#include <hip/hip_fp16.h>
#include <math.h>

// ---------------------------------------------------------------------------
// HyperbolicGraphConvolution (HGCN HypLinear + NodeSelect + HypAct), c=1.
// Round 20: fat-kernel overlap. binPlace (CSR bin pass, memory/atomic-bound,
// ~25-30us) and gemmprep (VALU-bound, ~111us) are independent -> one kernel,
// block-role split (blocks 0..255 = binPlace @512thr, rest = gemmprep). LDS
// aliased via shared char buffer. CSR intra-row order changes (score perturb
// ~1e-16, gaps ~5e-7 -> selection set unchanged). Rest identical to R19.
// ---------------------------------------------------------------------------

#define MAXN_D 0.996      // (1 - 4e-3)/sqrt(c), c=1
#define MAXN_F 0.996f
#define NPB 64            // nodes per gemmprep-role block (8 per wave, 8 waves)
#define GPT 512           // fat-kernel threads per block
#define NBMAX 512         // max buckets (N <= 131072)
#define BCAP 6144         // static bucket capacity (mean 3072, sigma 55)
#define BINBLK 256        // binPlace-role blocks
#define SELB 128          // blocks per select level
#define SBIN 8192         // 13-bit radix bins
#define CAND_CAP 16384    // finish-stage candidate cap (expect ~12)

typedef unsigned long long ull;

__device__ __forceinline__ double wsumd(double v){
#pragma unroll
  for(int o=32;o;o>>=1) v += __shfl_xor(v,o,64);
  return v;
}
__device__ __forceinline__ float wsumf(float v){
#pragma unroll
  for(int o=32;o;o>>=1) v += __shfl_xor(v,o,64);
  return v;
}
__device__ __forceinline__ float qsumf(float v){
#pragma unroll
  for(int o=1;o<16;o<<=1) v += __shfl_xor(v,o,64);
  return v;
}

// ---- K0: hyp_bias (double) + |hb|^2 + rem + static bucket cursors ----------
__global__ __launch_bounds__(256) void k_init(
    const float* __restrict__ bias, double* __restrict__ hb,
    double* __restrict__ hb2, int* __restrict__ rem, int kth,
    int* __restrict__ dstCur, int* __restrict__ srcCur, int NB){
  if(threadIdx.x < 64){
    int lane = threadIdx.x;
    double b = (double)bias[lane];
    double n = fmax(sqrt(wsumd(b*b)), 1e-15);
    double e = tanh(n)*b/n;                       // expmap0, sc=1
    double en = fmax(sqrt(wsumd(e*e)), 1e-15);
    if(en > MAXN_D) e *= MAXN_D/en;               // proj
    hb[lane] = e;
    double s2 = wsumd(e*e);
    if(lane==0) *hb2 = s2;
  }
  if(threadIdx.x == 0) *rem = kth;
  for(int b=threadIdx.x; b<NB; b+=256){
    dstCur[b] = b*BCAP;
    srcCur[b] = b*BCAP;
  }
}

// ---- K1: FAT kernel: blocks [0,binBlocks) = binPlace; rest = gemmprep ------
__global__ __launch_bounds__(GPT) void k_fat(
    // binPlace args
    const int* __restrict__ ei, int E, int NB, int chunk,
    int* __restrict__ dstCur, int* __restrict__ srcCur,
    ull* __restrict__ dstbin, int* __restrict__ srcbin, int binBlocks,
    // gemmprep args
    const float* __restrict__ x, const float* __restrict__ W,
    const double* __restrict__ hb, const double* __restrict__ hb2p,
    const float* __restrict__ lww,
    float* __restrict__ xtf, float* __restrict__ xdl, __half* __restrict__ xth,
    float2* __restrict__ pab, int N){
  __shared__ __align__(16) char smem[35328];
  int tid = threadIdx.x;

  if(blockIdx.x < (unsigned)binBlocks){
    // ================= binPlace role (512 threads) =========================
    int* dh  = (int*)smem;              // [NBMAX]
    int* sh_ = (int*)(smem + 2048);
    int* db  = (int*)(smem + 4096);
    int* sb  = (int*)(smem + 6144);
    for(int t=tid; t<NB; t+=GPT){ dh[t]=0; sh_[t]=0; }
    __syncthreads();
    int start = blockIdx.x*chunk, end = min(E, start+chunk);
    for(int e=start+tid; e<end; e+=GPT){
      int s = ei[e], d = ei[(size_t)E+e];
      atomicAdd(&dh[d>>8],1);
      if(s!=d) atomicAdd(&sh_[s>>8],1);
    }
    __syncthreads();
    for(int t=tid; t<NB; t+=GPT){
      db[t] = dh[t]  ? atomicAdd(&dstCur[t], dh[t])  : 0;
      sb[t] = sh_[t] ? atomicAdd(&srcCur[t], sh_[t]) : 0;
    }
    __syncthreads();
    for(int t=tid; t<NB; t+=GPT){ dh[t]=db[t]; sh_[t]=sb[t]; }
    __syncthreads();
    for(int e=start+tid; e<end; e+=GPT){
      int s = ei[e], d = ei[(size_t)E+e];
      int p = atomicAdd(&dh[d>>8],1);
      dstbin[p] = ((ull)(unsigned)d<<32) | (unsigned)s;
      if(s!=d){ int p2 = atomicAdd(&sh_[s>>8],1); srcbin[p2] = s; }
    }
    return;
  }

  // ================= gemmprep role =========================================
  float*  wf   = (float*)smem;                 // 16KB: [k4][j][m]
  float*  xf   = (float*)(smem + 16384);       // 16KB: [n][k]
  double (*r123)[3] = (double(*)[3])(smem + 32768);   // 1536B
  double (*abuf)[2] = (double(*)[2])(smem + 34304);   // 1024B
  for(int a=tid; a<4096; a+=GPT){   // linear LDS writes; W gathered from L1
    int j = (a>>2)&63;
    int k = ((a>>8)<<2) | (a&3);
    wf[a] = W[j*64 + k];
  }
  int i0 = (blockIdx.x - binBlocks)*NPB;
  for(int idx=tid; idx<NPB*64; idx+=GPT){
    int node = i0 + (idx>>6);
    xf[idx] = (node<N) ? x[(size_t)node*64 + (idx&63)] : 0.f;
  }
  __syncthreads();
  int lane = tid & 63;
  int nb = (tid>>6)*8;              // this wave's first node-in-block (8/wave)
  double acc0=0.0, acc1=0.0, acc2=0.0, acc3=0.0;
  double acc4=0.0, acc5=0.0, acc6=0.0, acc7=0.0;
  const float4* wq = (const float4*)wf;   // wq[k4*64 + lane]
  const float4* xq = (const float4*)xf;   // xq[node_local*16 + k4]
#pragma unroll 2
  for(int k4=0; k4<16; ++k4){
    float4 w4 = wq[k4*64 + lane];
    double w0=(double)w4.x, w1=(double)w4.y, w2d=(double)w4.z, w3=(double)w4.w;
#define MAC(n, accn) { float4 v = xq[(nb+(n))*16 + k4];                       \
    accn = fma(w0,(double)v.x,accn); accn = fma(w1,(double)v.y,accn);         \
    accn = fma(w2d,(double)v.z,accn); accn = fma(w3,(double)v.w,accn); }
    MAC(0,acc0) MAC(1,acc1) MAC(2,acc2) MAC(3,acc3)
    MAC(4,acc4) MAC(5,acc5) MAC(6,acc6) MAC(7,acc7)
#undef MAC
  }
  double hbl = hb[lane];
  // ---- reductions for 8 nodes -> r123 LDS ---------------------------------
#define RED4(A0,A1,A2,A3, OFF) {                                              \
    double xd0 = (double)xf[(nb+(OFF)+0)*64+lane];                            \
    double xd1 = (double)xf[(nb+(OFF)+1)*64+lane];                            \
    double xd2 = (double)xf[(nb+(OFF)+2)*64+lane];                            \
    double xd3 = (double)xf[(nb+(OFF)+3)*64+lane];                            \
    double s1_0 = wsumd(xd0*xd0), s2_0 = wsumd((A0)*(A0)), s3_0 = wsumd((A0)*hbl); \
    double s1_1 = wsumd(xd1*xd1), s2_1 = wsumd((A1)*(A1)), s3_1 = wsumd((A1)*hbl); \
    double s1_2 = wsumd(xd2*xd2), s2_2 = wsumd((A2)*(A2)), s3_2 = wsumd((A2)*hbl); \
    double s1_3 = wsumd(xd3*xd3), s2_3 = wsumd((A3)*(A3)), s3_3 = wsumd((A3)*hbl); \
    if(lane==0){                                                              \
      r123[nb+(OFF)+0][0]=s1_0; r123[nb+(OFF)+0][1]=s2_0; r123[nb+(OFF)+0][2]=s3_0; \
      r123[nb+(OFF)+1][0]=s1_1; r123[nb+(OFF)+1][1]=s2_1; r123[nb+(OFF)+1][2]=s3_1; \
      r123[nb+(OFF)+2][0]=s1_2; r123[nb+(OFF)+2][1]=s2_2; r123[nb+(OFF)+2][2]=s3_2; \
      r123[nb+(OFF)+3][0]=s1_3; r123[nb+(OFF)+3][1]=s2_3; r123[nb+(OFF)+3][2]=s3_3; \
    } }
  RED4(acc0,acc1,acc2,acc3, 0)
  RED4(acc4,acc5,acc6,acc7, 4)
#undef RED4
  __syncthreads();
  // ---- chain: wave 0 only, lane = node-in-block ---------------------------
  if(tid < 64){
    double x2s = r123[tid][0], m2 = r123[tid][1], mh = r123[tid][2];
    double y2 = *hb2p;
    double xn  = fmax(sqrt(x2s), 1e-15);
    double mxn = fmax(sqrt(m2), 1e-15);
    double xc  = fmin(fmax(xn, -1.0+1e-7), 1.0-1e-7);
    double at  = 0.5*(log1p(xc)-log1p(-xc));        // artanh(|x|)
    double f1  = tanh(mxn/xn*at)/mxn;               // h = f1*mx
    if(m2 == 0.0) f1 = 0.0;
    double h2 = f1*f1*m2;
    double hn = fmax(sqrt(h2), 1e-15);
    if(hn > MAXN_D){ double s = MAXN_D/hn; f1 *= s; h2 = f1*f1*m2; }   // proj(h)
    double xy = f1*mh;
    double den = fmax(1.0 + 2.0*xy + h2*y2, 1e-15);
    double a = (1.0 + 2.0*xy + y2)/den;
    double bb = (1.0 - h2)/den;
    double p2 = a*a*h2 + 2.0*a*bb*xy + bb*bb*y2;
    double pn = fmax(sqrt(p2), 1e-15);
    if(pn > MAXN_D){ double s = MAXN_D/pn; a*=s; bb*=s; pn = fmax(pn*s, 1e-15); }
    double nc  = fmin(fmax(pn, -1.0+1e-7), 1.0-1e-7);
    double at2 = 0.5*(log1p(nc)-log1p(-nc));        // artanh(|p|)
    double sc  = at2/pn;                            // logmap0 scale
    abuf[tid][0] = sc*a*f1;
    abuf[tid][1] = sc*bb;
  }
  __syncthreads();
  // ---- emit: xtf + f32 delta + f16 mirror ---------------------------------
  float wAl = lww[lane], wBl = lww[64+lane];
#define EMIT(n, accn) { int nd=i0+nb+(n); if(nd<N){                           \
    double al = abuf[nb+(n)][0], be = abuf[nb+(n)][1];                        \
    double v = al*(accn) + be*hbl;                                            \
    float vf = (float)v;                                                      \
    float df = (float)(v - (double)vf);                                       \
    xtf[(size_t)nd*64+lane] = vf;                                             \
    xdl[(size_t)nd*64+lane] = df;                                             \
    xth[(size_t)nd*64+lane] = __float2half(vf);                               \
    float pA = wsumf(vf*wAl);                                                 \
    float pB = wsumf(vf*wBl);                                                 \
    if(lane==0) pab[nd] = make_float2(pA,pB); } }
  EMIT(0,acc0) EMIT(1,acc1) EMIT(2,acc2) EMIT(3,acc3)
  EMIT(4,acc4) EMIT(5,acc5) EMIT(6,acc6) EMIT(7,acc7)
#undef EMIT
}

// ---- K2: per bucket: dst->rowbeg/rowcnt/csr, then src->dinv ----------------
__global__ __launch_bounds__(256) void k_bucketAB(
    const ull* __restrict__ dstbin, const int* __restrict__ dstCur,
    int* __restrict__ rowbeg, int* __restrict__ rowcnt, int* __restrict__ csr,
    const int* __restrict__ srcbin, const int* __restrict__ srcCur,
    double* __restrict__ dinv, int N){
  int b = blockIdx.x;
  int node0 = b<<8;
  int nodes = min(256, N-node0);
  __shared__ int c[256], ex[256];
  int t = threadIdx.x;
  {
    int base = b*BCAP, cnt = dstCur[b]-base;
    c[t]=0; __syncthreads();
    for(int e=base+t; e<base+cnt; e+=256){
      int d = (int)(dstbin[e]>>32);
      atomicAdd(&c[d-node0],1);
    }
    __syncthreads();
    int v = c[t]; ex[t]=v; __syncthreads();
    for(int off=1; off<256; off<<=1){
      int a = (t>=off) ? ex[t-off] : 0; __syncthreads();
      ex[t] += a; __syncthreads();
    }
    int mybase = base + ex[t] - v;
    if(t<nodes){ rowbeg[node0+t] = mybase; rowcnt[node0+t] = v; }
    c[t] = mybase;
    __syncthreads();
    for(int e=base+t; e<base+cnt; e+=256){
      ull pr = dstbin[e];
      int d = (int)(pr>>32);
      int p = atomicAdd(&c[d-node0],1);
      csr[p] = (int)(pr & 0xffffffffu);
    }
  }
  __syncthreads();
  {
    int base = b*BCAP, cnt = srcCur[b]-base;
    c[t]=0; __syncthreads();
    for(int e=base+t; e<base+cnt; e+=256)
      atomicAdd(&c[srcbin[e]-node0],1);
    __syncthreads();
    if(t<nodes){ int d = c[t]; dinv[node0+t] = (d>0) ? 1.0/sqrt((double)d) : 0.0; }
  }
}

// ---- K3: gather A: score key, 8 rows in flight (8 groups x 8 lanes) --------
__global__ void k_gatherA(const int* __restrict__ csr, const int* __restrict__ rowbeg,
                          const int* __restrict__ rowcnt,
                          const float* __restrict__ xtf, const float* __restrict__ xdl,
                          const double* __restrict__ dinv,
                          ull* __restrict__ keys, int N){
  int lane = threadIdx.x & 63;
  int i = (int)((blockIdx.x*(unsigned)blockDim.x + threadIdx.x)>>6);
  if(i>=N) return;
  int beg = rowbeg[i], deg = rowcnt[i];
  int g = lane>>3, t = lane&7;          // 8 groups of 8 lanes; lane covers 8 dims
  double di = dinv[i];
  double a0=0,a1=0,a2=0,a3=0,a4=0,a5=0,a6=0,a7=0;
  int j = g;
  int s = (j<deg) ? csr[beg+j] : 0;
  while(j < deg){
    int snext = (j+8<deg) ? csr[beg+j+8] : 0;       // prefetch next index
    if(s != i){
      double w = di*dinv[s];
      const float4* row = (const float4*)(xtf + (size_t)s*64 + t*8);
      float4 u = row[0], v = row[1];
      a0 -= w*(double)u.x; a1 -= w*(double)u.y; a2 -= w*(double)u.z; a3 -= w*(double)u.w;
      a4 -= w*(double)v.x; a5 -= w*(double)v.y; a6 -= w*(double)v.z; a7 -= w*(double)v.w;
    }
    s = snext; j += 8;
  }
#define XG(v) { v += __shfl_xor(v,8,64); v += __shfl_xor(v,16,64); v += __shfl_xor(v,32,64); }
  XG(a0) XG(a1) XG(a2) XG(a3) XG(a4) XG(a5) XG(a6) XG(a7)
#undef XG
  const float4* xr = (const float4*)(xtf + (size_t)i*64 + t*8);
  const float4* dr = (const float4*)(xdl + (size_t)i*64 + t*8);
  float4 x0 = xr[0], x1 = xr[1], d0 = dr[0], d1 = dr[1];
  double sc =
    fabs(((double)x0.x+(double)d0.x)+a0) + fabs(((double)x0.y+(double)d0.y)+a1) +
    fabs(((double)x0.z+(double)d0.z)+a2) + fabs(((double)x0.w+(double)d0.w)+a3) +
    fabs(((double)x1.x+(double)d1.x)+a4) + fabs(((double)x1.y+(double)d1.y)+a5) +
    fabs(((double)x1.z+(double)d1.z)+a6) + fabs(((double)x1.w+(double)d1.w)+a7);
  sc += __shfl_xor(sc,1,64); sc += __shfl_xor(sc,2,64); sc += __shfl_xor(sc,4,64);
  if(lane==0) keys[i] = (ull)__double_as_longlong(sc);
}

// ---- K4: one 13-bit radix level: LDS hist + global merge + ticketed pick ---
__global__ __launch_bounds__(256) void k_sel13(
    const ull* __restrict__ keys, int N,
    ull* __restrict__ pref, int* __restrict__ rem,
    int lev, int shift, int width,
    int* __restrict__ hist /*SBIN, zeroed*/, int* __restrict__ ticket){
  __shared__ int h[SBIN];
  __shared__ int part[256];
  __shared__ int lastflag, pickedD, pickedR;
  int t = threadIdx.x;
  for(int b=t; b<SBIN; b+=256) h[b] = 0;
  __syncthreads();
  ull p0 = *pref;
  int rem0 = *rem;
  int mask = (1<<width) - 1;
  for(int i = blockIdx.x*256 + t; i<N; i += SELB*256){
    ull kk = keys[i];
    if(lev==0 || (kk >> (shift+width)) == (p0 >> (shift+width)))
      atomicAdd(&h[(int)((kk>>shift)&mask)], 1);
  }
  __syncthreads();
  for(int b=t; b<SBIN; b+=256)
    if(h[b]) __hip_atomic_fetch_add(&hist[b], h[b],
                                    __ATOMIC_RELAXED, __HIP_MEMORY_SCOPE_AGENT);
  __threadfence();
  if(t==0){
    int tk = __hip_atomic_fetch_add(ticket, 1, __ATOMIC_ACQ_REL, __HIP_MEMORY_SCOPE_AGENT);
    lastflag = (tk == SELB-1);
  }
  __syncthreads();
  if(!lastflag) return;
  int base = SBIN-1 - 32*t;               // descending chunked scan
  int pt = 0;
  for(int m=0;m<32;m++)
    pt += __hip_atomic_load(&hist[base-m], __ATOMIC_RELAXED, __HIP_MEMORY_SCOPE_AGENT);
  part[t] = pt;
  __syncthreads();
  for(int off=1; off<256; off<<=1){
    int a = (t>=off) ? part[t-off] : 0; __syncthreads();
    part[t] += a; __syncthreads();
  }
  int cumt = part[t];
  int prev = (t==0) ? 0 : part[t-1];
  if(cumt >= rem0 && prev < rem0){
    int c = 0;
    for(int m=0;m<32;m++){
      int hv = __hip_atomic_load(&hist[base-m], __ATOMIC_RELAXED, __HIP_MEMORY_SCOPE_AGENT);
      c += hv;
      if(prev + c >= rem0){ pickedD = base-m; pickedR = rem0 - (prev + c - hv); break; }
    }
  }
  __syncthreads();
  if(t==0){
    *rem = pickedR;
    *pref = p0 | ((ull)pickedD << shift);
  }
}

// ---- K5: finish: compact 26-bit-prefix candidates, exact rank-select -------
__global__ __launch_bounds__(256) void k_finish(
    const ull* __restrict__ keys, int N,
    ull* __restrict__ pref, const int* __restrict__ rem,
    ull* __restrict__ cand, int* __restrict__ cnt, int* __restrict__ ticket){
  __shared__ ull sc[4096];
  __shared__ int lastflag;
  __shared__ ull winner;
  int t = threadIdx.x;
  ull p0 = *pref;                          // bits 63..38 fixed, low bits 0
  for(int i = blockIdx.x*256 + t; i<N; i += SELB*256){
    ull kk = keys[i];
    if((kk>>38) == (p0>>38)){
      int idx = __hip_atomic_fetch_add(cnt, 1, __ATOMIC_RELAXED, __HIP_MEMORY_SCOPE_AGENT);
      if(idx < CAND_CAP)
        __hip_atomic_store(&cand[idx], kk, __ATOMIC_RELAXED, __HIP_MEMORY_SCOPE_AGENT);
    }
  }
  __threadfence();
  __syncthreads();
  if(t==0){
    int tk = __hip_atomic_fetch_add(ticket, 1, __ATOMIC_ACQ_REL, __HIP_MEMORY_SCOPE_AGENT);
    lastflag = (tk == SELB-1);
  }
  __syncthreads();
  if(!lastflag) return;
  int C = __hip_atomic_load(cnt, __ATOMIC_RELAXED, __HIP_MEMORY_SCOPE_AGENT);
  if(C > 4096) C = 4096;                   // expected C ~ 12
  for(int j=t; j<C; j+=256)
    sc[j] = __hip_atomic_load(&cand[j], __ATOMIC_RELAXED, __HIP_MEMORY_SCOPE_AGENT);
  __syncthreads();
  int r = *rem;                            // rank within prefix group (1-based)
  for(int j=t; j<C; j+=256){
    ull c = sc[j];
    int gt=0, eq=0;
    for(int m=0;m<C;m++){ ull o = sc[m]; gt += (o>c); eq += (o==c); }
    if(gt <= r-1 && r-1 < gt+eq) winner = c;
  }
  __syncthreads();
  if(t==0) *pref = winner;                 // full exact k-th largest key
}

// ---- K6: q[i] = pB + sel*pA (per-source gate contribution) -----------------
__global__ void k_qval(const float2* __restrict__ pab, const ull* __restrict__ keys,
                       const ull* __restrict__ pref, float* __restrict__ q, int N){
  int i = blockIdx.x*blockDim.x + threadIdx.x;
  if(i>=N) return;
  float2 p = pab[i];
  q[i] = p.y + ((keys[i] > *pref) ? p.x : 0.f);
}

// ---- K7: gather C: z = sum q[src]; gg = sel * sigmoid(z+b) -----------------
__global__ void k_gatherC(const int* __restrict__ csr, const int* __restrict__ rowbeg,
                          const int* __restrict__ rowcnt,
                          const float* __restrict__ q,
                          const ull* __restrict__ keys, const ull* __restrict__ pref,
                          const float* __restrict__ lwb,
                          float* __restrict__ gg, int N){
  int lane = threadIdx.x & 63;
  int wid  = (int)((blockIdx.x*(unsigned)blockDim.x + threadIdx.x)>>6);
  int g = lane>>4, t = lane&15;
  int i = wid*4 + g;
  if(i>=N) return;
  int beg = rowbeg[i], end = beg + rowcnt[i];
  float z = 0.f;
  for(int e = beg + t; e < end; e += 16) z += q[csr[e]];
  z = qsumf(z);
  if(t==0){
    float gv = 1.f/(1.f+expf(-(z + lwb[0])));
    gg[i] = (keys[i] > *pref) ? gv : 0.f;
  }
}

// ---- K8: gather D + final chain, 8 f16 rows in flight ----------------------
__global__ void k_gatherD(const int* __restrict__ csr, const int* __restrict__ rowbeg,
                          const int* __restrict__ rowcnt,
                          const float* __restrict__ xtf, const __half* __restrict__ xth,
                          const float* __restrict__ gg,
                          float* __restrict__ out, int N){
  int lane = threadIdx.x & 63;
  int i = (int)((blockIdx.x*(unsigned)blockDim.x + threadIdx.x)>>6);
  if(i>=N) return;
  int beg = rowbeg[i], deg = rowcnt[i];
  int g = lane>>3, t = lane&7;          // 8 groups of 8 lanes; lane covers 8 dims
  float c0=0,c1=0,c2=0,c3=0,c4=0,c5=0,c6=0,c7=0;
  int j = g;
  int s = (j<deg) ? csr[beg+j] : 0;
  while(j < deg){
    int snext = (j+8<deg) ? csr[beg+j+8] : 0;
    float gv = gg[s];
    if(gv != 0.f){
      float4 raw = *(const float4*)(xth + (size_t)s*64 + t*8);   // 8 halves, 16B
      const __half2* hp = (const __half2*)&raw;
      float2 p0 = __half22float2(hp[0]);
      float2 p1 = __half22float2(hp[1]);
      float2 p2 = __half22float2(hp[2]);
      float2 p3 = __half22float2(hp[3]);
      c0 = fmaf(gv,p0.x,c0); c1 = fmaf(gv,p0.y,c1); c2 = fmaf(gv,p1.x,c2); c3 = fmaf(gv,p1.y,c3);
      c4 = fmaf(gv,p2.x,c4); c5 = fmaf(gv,p2.y,c5); c6 = fmaf(gv,p3.x,c6); c7 = fmaf(gv,p3.y,c7);
    }
    s = snext; j += 8;
  }
#define XG(v) { v += __shfl_xor(v,8,64); v += __shfl_xor(v,16,64); v += __shfl_xor(v,32,64); }
  XG(c0) XG(c1) XG(c2) XG(c3) XG(c4) XG(c5) XG(c6) XG(c7)
#undef XG
  const float4* xr = (const float4*)(xtf + (size_t)i*64 + t*8);
  float4 x0 = xr[0], x1 = xr[1];
  float v0 = x0.x + fmaxf(c0,0.f), v1 = x0.y + fmaxf(c1,0.f);
  float v2 = x0.z + fmaxf(c2,0.f), v3 = x0.w + fmaxf(c3,0.f);
  float v4 = x1.x + fmaxf(c4,0.f), v5 = x1.y + fmaxf(c5,0.f);
  float v6 = x1.z + fmaxf(c6,0.f), v7 = x1.w + fmaxf(c7,0.f);
  float n2 = v0*v0+v1*v1+v2*v2+v3*v3+v4*v4+v5*v5+v6*v6+v7*v7;
  n2 += __shfl_xor(n2,1,64); n2 += __shfl_xor(n2,2,64); n2 += __shfl_xor(n2,4,64);
  float n = fmaxf(sqrtf(n2), 1e-15f);
  float f = tanhf(n)/n;                                // expmap0 scale
  float e0=f*v0,e1=f*v1,e2=f*v2,e3=f*v3,e4=f*v4,e5=f*v5,e6=f*v6,e7=f*v7;
  float en = fmaxf(tanhf(n), 1e-15f);                  // |e| = tanh(n)
  if(en > MAXN_F){ float sf = MAXN_F/en;
    e0*=sf;e1*=sf;e2*=sf;e3*=sf;e4*=sf;e5*=sf;e6*=sf;e7*=sf; }
  e0=fmaxf(e0,0.f);e1=fmaxf(e1,0.f);e2=fmaxf(e2,0.f);e3=fmaxf(e3,0.f);
  e4=fmaxf(e4,0.f);e5=fmaxf(e5,0.f);e6=fmaxf(e6,0.f);e7=fmaxf(e7,0.f);
  float m2 = e0*e0+e1*e1+e2*e2+e3*e3+e4*e4+e5*e5+e6*e6+e7*e7;
  m2 += __shfl_xor(m2,1,64); m2 += __shfl_xor(m2,2,64); m2 += __shfl_xor(m2,4,64);
  float nb = fmaxf(sqrtf(m2), 1e-15f);
  float f2 = tanhf(nb)/nb;
  float o0=f2*e0,o1=f2*e1,o2=f2*e2,o3=f2*e3,o4=f2*e4,o5=f2*e5,o6=f2*e6,o7=f2*e7;
  float on = fmaxf(tanhf(nb), 1e-15f);
  if(on > MAXN_F){ float sf = MAXN_F/on;
    o0*=sf;o1*=sf;o2*=sf;o3*=sf;o4*=sf;o5*=sf;o6*=sf;o7*=sf; }
  if(g==0){
    float4* op = (float4*)(out + (size_t)i*64 + t*8);
    op[0] = make_float4(o0,o1,o2,o3);
    op[1] = make_float4(o4,o5,o6,o7);
  }
}

// ---------------------------------------------------------------------------
extern "C" void kernel_launch(void* const* d_in, const int* in_sizes, int n_in,
                              void* d_out, int out_size, void* d_ws, size_t ws_size,
                              hipStream_t stream){
  const float* x    = (const float*)d_in[0];
  const int*   ei   = (const int*)d_in[1];
  const float* W    = (const float*)d_in[2];
  const float* bias = (const float*)d_in[3];
  const float* lww  = (const float*)d_in[4];
  const float* lwb  = (const float*)d_in[5];
  int N = in_sizes[0]/64;
  int E = in_sizes[1]/2;
  int kth = (int)((double)N*0.75);
  int NB = (N+255)>>8;                         // node buckets (256 nodes each)
  if(NB > NBMAX) return;                       // loud failure if N too large
  long long meanPB = (long long)E / (NB > 0 ? NB : 1);
  if(3*meanPB > 2*(long long)BCAP) return;     // require BCAP >= 1.5x mean
  int chunk = (E + BINBLK - 1)/BINBLK;
  size_t binEls = (size_t)NB*BCAP + 4096;      // +slack (OOB insurance)

  char* ws = (char*)d_ws;
  size_t cur = 0;
  auto alloc = [&](size_t bytes){ size_t o = cur; cur = (cur + bytes + 255) & ~(size_t)255; return o; };
  size_t o_hb   = alloc(64*sizeof(double));
  size_t o_hb2  = alloc(8);
  size_t o_rem  = alloc(4);
  size_t o_zero = cur;                         // ---- zeroed region start ----
  size_t o_pref = alloc(8);                    // radix prefix (must start 0)
  size_t o_hist = alloc(2*(size_t)SBIN*4);     // per-level 13-bit hist
  size_t o_tick = alloc(3*4);                  // lev0, lev1, finish tickets
  size_t o_cnt  = alloc(4);                    // candidate count
  size_t zlen   = cur - o_zero;                // ---- zeroed region end ------
  size_t o_cand = alloc((size_t)CAND_CAP*8);
  size_t o_dCur = alloc((size_t)NBMAX*4);
  size_t o_sCur = alloc((size_t)NBMAX*4);
  size_t o_rbeg = alloc((size_t)N*4);
  size_t o_rcnt = alloc((size_t)N*4);
  size_t o_csr  = alloc(binEls*4);
  size_t o_dbin = alloc(binEls*8);
  size_t o_sbin = alloc(binEls*4);
  size_t o_dinv = alloc((size_t)N*8);
  size_t o_keys = alloc((size_t)N*8);
  size_t o_pab  = alloc((size_t)N*8);
  size_t o_q    = alloc((size_t)N*4);
  size_t o_xtf  = alloc((size_t)N*64*4);
  size_t o_xdl  = alloc((size_t)N*64*4);
  size_t o_xth  = alloc((size_t)N*64*2);
  size_t o_gg   = alloc((size_t)N*4);
  if(ws_size < cur) return;                    // loud, clean failure

  double* hb     = (double*)(ws+o_hb);
  double* hb2    = (double*)(ws+o_hb2);
  int*    rem    = (int*)(ws+o_rem);
  ull*    pref   = (ull*)(ws+o_pref);
  int*    hist   = (int*)(ws+o_hist);
  int*    tick   = (int*)(ws+o_tick);
  int*    cnt    = (int*)(ws+o_cnt);
  ull*    cand   = (ull*)(ws+o_cand);
  int*    dstCur = (int*)(ws+o_dCur);
  int*    srcCur = (int*)(ws+o_sCur);
  int*    rowbeg = (int*)(ws+o_rbeg);
  int*    rowcnt = (int*)(ws+o_rcnt);
  int*    csr    = (int*)(ws+o_csr);
  ull*    dstbin = (ull*)(ws+o_dbin);
  int*    srcbin = (int*)(ws+o_sbin);
  double* dinv   = (double*)(ws+o_dinv);
  ull*    keys   = (ull*)(ws+o_keys);
  float2* pab    = (float2*)(ws+o_pab);
  float*  q      = (float*)(ws+o_q);
  float*  xtf    = (float*)(ws+o_xtf);
  float*  xdl    = (float*)(ws+o_xdl);
  __half* xth    = (__half*)(ws+o_xth);
  float*  gg     = (float*)(ws+o_gg);

  hipMemsetAsync(ws+o_zero, 0, zlen, stream);

  int nodeBlocks = (N+3)/4;                    // 1 wave per node
  int pBlocks    = (N+15)/16;                  // 4 nodes per wave
  int gpBlocks   = (N+NPB-1)/NPB;              // gemmprep-role blocks

  k_init     <<<1, 256, 0, stream>>>(bias, hb, hb2, rem, kth, dstCur, srcCur, NB);
  k_fat      <<<BINBLK + gpBlocks, GPT, 0, stream>>>(
                 ei, E, NB, chunk, dstCur, srcCur, dstbin, srcbin, BINBLK,
                 x, W, hb, hb2, lww, xtf, xdl, xth, pab, N);
  k_bucketAB <<<NB, 256, 0, stream>>>(dstbin, dstCur, rowbeg, rowcnt, csr,
                                      srcbin, srcCur, dinv, N);
  k_gatherA  <<<nodeBlocks, 256, 0, stream>>>(csr, rowbeg, rowcnt, xtf, xdl, dinv, keys, N);
  k_sel13    <<<SELB, 256, 0, stream>>>(keys, N, pref, rem, 0, 51, 13, hist, tick+0);
  k_sel13    <<<SELB, 256, 0, stream>>>(keys, N, pref, rem, 1, 38, 13, hist+SBIN, tick+1);
  k_finish   <<<SELB, 256, 0, stream>>>(keys, N, pref, rem, cand, cnt, tick+2);
  k_qval     <<<(N+255)/256, 256, 0, stream>>>(pab, keys, pref, q, N);
  k_gatherC  <<<pBlocks, 256, 0, stream>>>(csr, rowbeg, rowcnt, q, keys, pref, lwb, gg, N);
  k_gatherD  <<<nodeBlocks, 256, 0, stream>>>(csr, rowbeg, rowcnt, xtf, xth, gg, (float*)d_out, N);
}